// Round 3
// baseline (2505.398 us; speedup 1.0000x reference)
//
#include <hip/hip_runtime.h>
#include <math.h>

#define B_ 64
#define I_ 2048
#define K_ 16
#define N_ 32
#define D_ 32
#define CH_ 32      // i-chunks of 64 i each
#define SUB_ 16     // i per LDS staging sub-chunk (32 KB)

// ws offsets (floats)
#define OFF_INT   0u           // inT   [I][K][B]     2097152
#define OFF_CT    2097152u     // cT    [N][I][B]     4194304
#define OFF_BT    6291456u     // bT    [N][I][B]     4194304
#define OFF_SPART 10485760u    // spart [N][CH][B][D] 2097152
#define OFF_OUTT  12582912u    // outT  [N][D][B]     65536
// total 12648448 floats = 48.25 MB

// ---------------- transpose inputs[b][i][k] -> inT[i][k][b] ----------------
__global__ __launch_bounds__(256) void k_transpose(const float* __restrict__ in,
                                                   float* __restrict__ inT) {
    __shared__ float lds[B_][K_ + 1];
    const int i = blockIdx.x;
    const int t = threadIdx.x;
    const int b = t >> 2, kq = t & 3;
    const float4 v = *(const float4*)(in + ((size_t)b * I_ + i) * K_ + kq * 4);
    lds[b][kq * 4 + 0] = v.x; lds[b][kq * 4 + 1] = v.y;
    lds[b][kq * 4 + 2] = v.z; lds[b][kq * 4 + 3] = v.w;
    __syncthreads();
#pragma unroll
    for (int q = 0; q < 4; ++q) {
        const int j = t + q * 256;          // j = k*64 + b
        const int k = j >> 6, bb = j & 63;
        inT[(size_t)i * (K_ * B_) + j] = lds[bb][k];
    }
}

#define DOT16(xreg, w0, w1, w2, w3) \
    (xreg[0]*w0.x + xreg[1]*w0.y + xreg[2]*w0.z + xreg[3]*w0.w + \
     xreg[4]*w1.x + xreg[5]*w1.y + xreg[6]*w1.z + xreg[7]*w1.w + \
     xreg[8]*w2.x + xreg[9]*w2.y + xreg[10]*w2.z + xreg[11]*w2.w + \
     xreg[12]*w3.x + xreg[13]*w3.y + xreg[14]*w3.z + xreg[15]*w3.w)

// stage SUB_*512 floats (= 2048 float4) with 256 threads: 8 float4 each
#define STAGE_W(dstp, srcp, t) \
    { const float4* _s = (const float4*)(srcp); float4* _d = (float4*)(dstp); \
      _Pragma("unroll") \
      for (int _q = 0; _q < 8; ++_q) _d[(t) + _q * 256] = _s[(t) + _q * 256]; }

// ---------------- s-sweep: spart[n][ch][b][d] = sum_{i in chunk} c * u_hat --------
template<int UNIFORM>
__global__ __launch_bounds__(256, 4) void k_sweep(const float* __restrict__ W,
                                                  const float* __restrict__ inT,
                                                  const float* __restrict__ cT,
                                                  float* __restrict__ spart) {
    __shared__ __align__(16) float smem[4 * B_ * (D_ + 1)];   // 8448 f >= 8192 stage
    const int n = blockIdx.y, ch = blockIdx.x;
    const int t = threadIdx.x, w = t >> 6, lane = t & 63;   // lane = b

    float acc[D_];
#pragma unroll
    for (int d = 0; d < D_; ++d) acc[d] = 0.f;

    const float* wg = W + (size_t)(n * I_ + ch * 64) * (D_ * K_);

    for (int sc = 0; sc < 4; ++sc) {
        if (sc) __syncthreads();
        STAGE_W(smem, wg + sc * (SUB_ * 512), t);
        __syncthreads();

#pragma unroll
        for (int q = 0; q < 4; ++q) {
            const int il = w * 4 + q;                 // row in sub-chunk
            const int i  = ch * 64 + sc * SUB_ + il;
            const float c = UNIFORM ? (1.0f / N_)
                                    : cT[((size_t)n * I_ + i) * B_ + lane];
            const float* xp = inT + (size_t)i * (K_ * B_) + lane;
            float xc[K_];
#pragma unroll
            for (int k = 0; k < K_; ++k) xc[k] = c * xp[k * B_];
            const float* wl = smem + il * 512;
#pragma unroll
            for (int d = 0; d < D_; ++d) {
                const float4* w4 = (const float4*)(wl + d * K_);
                const float4 w0 = w4[0], w1 = w4[1], w2 = w4[2], w3 = w4[3];
                acc[d] += DOT16(xc, w0, w1, w2, w3);
            }
        }
    }

    __syncthreads();
    float (*red)[B_][D_ + 1] = (float (*)[B_][D_ + 1])smem;
#pragma unroll
    for (int d = 0; d < D_; ++d) red[w][lane][d] = acc[d];
    __syncthreads();
#pragma unroll
    for (int q = 0; q < 8; ++q) {
        const int j = t + q * 256;                    // j = b*32 + d
        const int b = j >> 5, d = j & 31;
        const float s = red[0][b][d] + red[1][b][d] + red[2][b][d] + red[3][b][d];
        spart[((size_t)n * CH_ + ch) * (B_ * D_) + j] = s;
    }
}

// ---------------- reduce partials + squash ----------------
template<int FINAL>
__global__ __launch_bounds__(256) void k_reduce(const float* __restrict__ spart,
                                                float* __restrict__ outT,
                                                float* __restrict__ out) {
    const int gt = blockIdx.x * 256 + threadIdx.x;   // N*B*D threads
    const int n = gt >> 11;
    const int rem = gt & 2047;                        // b*32 + d
    const int b = rem >> 5, d = rem & 31;
    const float* sp = spart + (size_t)n * (CH_ * B_ * D_) + rem;
    float s = 0.f;
#pragma unroll 8
    for (int p = 0; p < CH_; ++p) s += sp[p * (B_ * D_)];

    float sq = s * s;
#pragma unroll
    for (int off = 16; off >= 1; off >>= 1) sq += __shfl_xor(sq, off, 64);
    const float scale = sq / ((1.0f + sq) * sqrtf(sq + 1e-7f));
    const float o = scale * s;
    if (FINAL) {
        out[((size_t)b * N_ + n) * D_ + d] = o;       // [B][N][D]
    } else {
        outT[((size_t)n * D_ + d) * B_ + b] = o;      // [N][D][B]
    }
}

// ---------------- logits: bT[n][i][b] (+)= sum_d out*u_hat ----------------
template<int FIRST>
__global__ __launch_bounds__(256, 4) void k_update(const float* __restrict__ W,
                                                   const float* __restrict__ inT,
                                                   const float* __restrict__ outT,
                                                   float* __restrict__ bT) {
    __shared__ __align__(16) float smem[SUB_ * 512];
    const int n = blockIdx.y, ch = blockIdx.x;
    const int t = threadIdx.x, w = t >> 6, lane = t & 63;   // lane = b

    float o[D_];
#pragma unroll
    for (int d = 0; d < D_; ++d) o[d] = outT[(size_t)n * (D_ * B_) + d * B_ + lane];

    const float* wg = W + (size_t)(n * I_ + ch * 64) * (D_ * K_);

    for (int sc = 0; sc < 4; ++sc) {
        if (sc) __syncthreads();
        STAGE_W(smem, wg + sc * (SUB_ * 512), t);
        __syncthreads();

#pragma unroll
        for (int q = 0; q < 4; ++q) {
            const int il = w * 4 + q;
            const int i  = ch * 64 + sc * SUB_ + il;
            const float* xp = inT + (size_t)i * (K_ * B_) + lane;
            float x[K_];
#pragma unroll
            for (int k = 0; k < K_; ++k) x[k] = xp[k * B_];
            const float* wl = smem + il * 512;
            float g = 0.f;
#pragma unroll
            for (int d = 0; d < D_; ++d) {
                const float4* w4 = (const float4*)(wl + d * K_);
                const float4 w0 = w4[0], w1 = w4[1], w2 = w4[2], w3 = w4[3];
                const float u = DOT16(x, w0, w1, w2, w3);
                g = fmaf(o[d], u, g);
            }
            const size_t bi = ((size_t)n * I_ + i) * B_ + lane;
            bT[bi] = FIRST ? g : (bT[bi] + g);
        }
    }
}

// ---------------- softmax over n: cT[n][i][b] = softmax_n(bT) ----------------
__global__ __launch_bounds__(256) void k_softmax(const float* __restrict__ bT,
                                                 float* __restrict__ cT) {
    const int t = threadIdx.x, w = t >> 6, lane = t & 63;
    const int i = blockIdx.x * 4 + w;
    float v[N_];
#pragma unroll
    for (int n = 0; n < N_; ++n) v[n] = bT[((size_t)n * I_ + i) * B_ + lane];
    float m = v[0];
#pragma unroll
    for (int n = 1; n < N_; ++n) m = fmaxf(m, v[n]);
    float sum = 0.f;
#pragma unroll
    for (int n = 0; n < N_; ++n) { v[n] = __expf(v[n] - m); sum += v[n]; }
    const float inv = 1.0f / sum;
#pragma unroll
    for (int n = 0; n < N_; ++n)
        cT[((size_t)n * I_ + i) * B_ + lane] = v[n] * inv;
}

extern "C" void kernel_launch(void* const* d_in, const int* in_sizes, int n_in,
                              void* d_out, int out_size, void* d_ws, size_t ws_size,
                              hipStream_t stream) {
    const float* inputs = (const float*)d_in[0];
    const float* W      = (const float*)d_in[1];
    float* out = (float*)d_out;
    float* ws  = (float*)d_ws;
    float* inT   = ws + OFF_INT;
    float* cT    = ws + OFF_CT;
    float* bT    = ws + OFF_BT;
    float* spart = ws + OFF_SPART;
    float* outT  = ws + OFF_OUTT;

    k_transpose<<<I_, 256, 0, stream>>>(inputs, inT);
    // r = 0 (c uniform = 1/N since b=0)
    k_sweep<1><<<dim3(CH_, N_), 256, 0, stream>>>(W, inT, cT, spart);
    k_reduce<0><<<256, 256, 0, stream>>>(spart, outT, out);
    k_update<1><<<dim3(CH_, N_), 256, 0, stream>>>(W, inT, outT, bT);
    k_softmax<<<I_ / 4, 256, 0, stream>>>(bT, cT);
    // r = 1
    k_sweep<0><<<dim3(CH_, N_), 256, 0, stream>>>(W, inT, cT, spart);
    k_reduce<0><<<256, 256, 0, stream>>>(spart, outT, out);
    k_update<0><<<dim3(CH_, N_), 256, 0, stream>>>(W, inT, outT, bT);
    k_softmax<<<I_ / 4, 256, 0, stream>>>(bT, cT);
    // r = 2
    k_sweep<0><<<dim3(CH_, N_), 256, 0, stream>>>(W, inT, cT, spart);
    k_reduce<1><<<256, 256, 0, stream>>>(spart, outT, out);
}

// Round 4
// 1351.246 us; speedup vs baseline: 1.8541x; 1.8541x over previous
//
#include <hip/hip_runtime.h>
#include <math.h>

#define B_ 64
#define I_ 2048
#define K_ 16
#define N_ 32
#define D_ 32
#define CH_ 32      // i-chunks of 64 i each
#define SUB_ 16     // i per LDS staging sub-chunk (32 KB)

// ws offsets (floats)
#define OFF_INT   0u           // inT   [I][K][B]     2097152
#define OFF_CT    2097152u     // cT    [N][I][B]     4194304
#define OFF_BT    6291456u     // bT    [N][I][B]     4194304
#define OFF_SPART 10485760u    // spart [N][CH][B][D] 2097152
#define OFF_OUTT  12582912u    // outT  [N][D][B]     65536
// total 12648448 floats = 48.25 MB

// ---------------- transpose inputs[b][i][k] -> inT[i][k][b] ----------------
__global__ __launch_bounds__(256) void k_transpose(const float* __restrict__ in,
                                                   float* __restrict__ inT) {
    __shared__ float lds[B_][K_ + 1];
    const int i = blockIdx.x;
    const int t = threadIdx.x;
    const int b = t >> 2, kq = t & 3;
    const float4 v = *(const float4*)(in + ((size_t)b * I_ + i) * K_ + kq * 4);
    lds[b][kq * 4 + 0] = v.x; lds[b][kq * 4 + 1] = v.y;
    lds[b][kq * 4 + 2] = v.z; lds[b][kq * 4 + 3] = v.w;
    __syncthreads();
#pragma unroll
    for (int q = 0; q < 4; ++q) {
        const int j = t + q * 256;          // j = k*64 + b
        const int k = j >> 6, bb = j & 63;
        inT[(size_t)i * (K_ * B_) + j] = lds[bb][k];
    }
}

#define DOT16(xreg, w0, w1, w2, w3) \
    (xreg[0]*w0.x + xreg[1]*w0.y + xreg[2]*w0.z + xreg[3]*w0.w + \
     xreg[4]*w1.x + xreg[5]*w1.y + xreg[6]*w1.z + xreg[7]*w1.w + \
     xreg[8]*w2.x + xreg[9]*w2.y + xreg[10]*w2.z + xreg[11]*w2.w + \
     xreg[12]*w3.x + xreg[13]*w3.y + xreg[14]*w3.z + xreg[15]*w3.w)

// stage SUB_*512 floats (= 2048 float4) with 256 threads: 8 float4 each
#define STAGE_W(dstp, srcp, t) \
    { const float4* _s = (const float4*)(srcp); float4* _d = (float4*)(dstp); \
      _Pragma("unroll") \
      for (int _q = 0; _q < 8; ++_q) _d[(t) + _q * 256] = _s[(t) + _q * 256]; }

// ---------------- s-sweep: spart[n][ch][b][d] = sum_{i in chunk} c * u_hat --------
template<int UNIFORM>
__global__ __launch_bounds__(256, 2) void k_sweep(const float* __restrict__ W,
                                                  const float* __restrict__ inT,
                                                  const float* __restrict__ cT,
                                                  float* __restrict__ spart) {
    __shared__ __align__(16) float smem[4 * B_ * (D_ + 1)];   // 8448 f >= 8192 stage
    const int n = blockIdx.y, ch = blockIdx.x;
    const int t = threadIdx.x, w = t >> 6, lane = t & 63;   // lane = b

    float acc[D_];
#pragma unroll
    for (int d = 0; d < D_; ++d) acc[d] = 0.f;

    const float* wg = W + (size_t)(n * I_ + ch * 64) * (D_ * K_);

    for (int sc = 0; sc < 4; ++sc) {
        if (sc) __syncthreads();
        STAGE_W(smem, wg + sc * (SUB_ * 512), t);
        __syncthreads();

#pragma unroll
        for (int q = 0; q < 4; ++q) {
            const int il = w * 4 + q;                 // row in sub-chunk
            const int i  = ch * 64 + sc * SUB_ + il;
            const float c = UNIFORM ? (1.0f / N_)
                                    : cT[((size_t)n * I_ + i) * B_ + lane];
            const float* xp = inT + (size_t)i * (K_ * B_) + lane;
            float xc[K_];
#pragma unroll
            for (int k = 0; k < K_; ++k) xc[k] = c * xp[k * B_];
            const float* wl = smem + il * 512;
#pragma unroll
            for (int d = 0; d < D_; ++d) {
                const float4* w4 = (const float4*)(wl + d * K_);
                const float4 w0 = w4[0], w1 = w4[1], w2 = w4[2], w3 = w4[3];
                acc[d] += DOT16(xc, w0, w1, w2, w3);
            }
        }
    }

    __syncthreads();
    float (*red)[B_][D_ + 1] = (float (*)[B_][D_ + 1])smem;
#pragma unroll
    for (int d = 0; d < D_; ++d) red[w][lane][d] = acc[d];
    __syncthreads();
#pragma unroll
    for (int q = 0; q < 8; ++q) {
        const int j = t + q * 256;                    // j = b*32 + d
        const int b = j >> 5, d = j & 31;
        const float s = red[0][b][d] + red[1][b][d] + red[2][b][d] + red[3][b][d];
        spart[((size_t)n * CH_ + ch) * (B_ * D_) + j] = s;
    }
}

// ---------------- reduce partials + squash ----------------
template<int FINAL>
__global__ __launch_bounds__(256) void k_reduce(const float* __restrict__ spart,
                                                float* __restrict__ outT,
                                                float* __restrict__ out) {
    const int gt = blockIdx.x * 256 + threadIdx.x;   // N*B*D threads
    const int n = gt >> 11;
    const int rem = gt & 2047;                        // b*32 + d
    const int b = rem >> 5, d = rem & 31;
    const float* sp = spart + (size_t)n * (CH_ * B_ * D_) + rem;
    float s = 0.f;
#pragma unroll 8
    for (int p = 0; p < CH_; ++p) s += sp[p * (B_ * D_)];

    float sq = s * s;
#pragma unroll
    for (int off = 16; off >= 1; off >>= 1) sq += __shfl_xor(sq, off, 64);
    const float scale = sq / ((1.0f + sq) * sqrtf(sq + 1e-7f));
    const float o = scale * s;
    if (FINAL) {
        out[((size_t)b * N_ + n) * D_ + d] = o;       // [B][N][D]
    } else {
        outT[((size_t)n * D_ + d) * B_ + b] = o;      // [N][D][B]
    }
}

// ---------------- logits: bT[n][i][b] (+)= sum_d out*u_hat ----------------
template<int FIRST>
__global__ __launch_bounds__(256, 2) void k_update(const float* __restrict__ W,
                                                   const float* __restrict__ inT,
                                                   const float* __restrict__ outT,
                                                   float* __restrict__ bT) {
    __shared__ __align__(16) float smem[SUB_ * 512];
    const int n = blockIdx.y, ch = blockIdx.x;
    const int t = threadIdx.x, w = t >> 6, lane = t & 63;   // lane = b

    float o[D_];
#pragma unroll
    for (int d = 0; d < D_; ++d) o[d] = outT[(size_t)n * (D_ * B_) + d * B_ + lane];

    const float* wg = W + (size_t)(n * I_ + ch * 64) * (D_ * K_);

    for (int sc = 0; sc < 4; ++sc) {
        if (sc) __syncthreads();
        STAGE_W(smem, wg + sc * (SUB_ * 512), t);
        __syncthreads();

#pragma unroll
        for (int q = 0; q < 4; ++q) {
            const int il = w * 4 + q;
            const int i  = ch * 64 + sc * SUB_ + il;
            const float* xp = inT + (size_t)i * (K_ * B_) + lane;
            float x[K_];
#pragma unroll
            for (int k = 0; k < K_; ++k) x[k] = xp[k * B_];
            const float* wl = smem + il * 512;
            float g = 0.f;
#pragma unroll
            for (int d = 0; d < D_; ++d) {
                const float4* w4 = (const float4*)(wl + d * K_);
                const float4 w0 = w4[0], w1 = w4[1], w2 = w4[2], w3 = w4[3];
                const float u = DOT16(x, w0, w1, w2, w3);
                g = fmaf(o[d], u, g);
            }
            const size_t bi = ((size_t)n * I_ + i) * B_ + lane;
            bT[bi] = FIRST ? g : (bT[bi] + g);
        }
    }
}

// ---------------- softmax over n: cT[n][i][b] = softmax_n(bT) ----------------
__global__ __launch_bounds__(256) void k_softmax(const float* __restrict__ bT,
                                                 float* __restrict__ cT) {
    const int t = threadIdx.x, w = t >> 6, lane = t & 63;
    const int i = blockIdx.x * 4 + w;
    float v[N_];
#pragma unroll
    for (int n = 0; n < N_; ++n) v[n] = bT[((size_t)n * I_ + i) * B_ + lane];
    float m = v[0];
#pragma unroll
    for (int n = 1; n < N_; ++n) m = fmaxf(m, v[n]);
    float sum = 0.f;
#pragma unroll
    for (int n = 0; n < N_; ++n) { v[n] = __expf(v[n] - m); sum += v[n]; }
    const float inv = 1.0f / sum;
#pragma unroll
    for (int n = 0; n < N_; ++n)
        cT[((size_t)n * I_ + i) * B_ + lane] = v[n] * inv;
}

extern "C" void kernel_launch(void* const* d_in, const int* in_sizes, int n_in,
                              void* d_out, int out_size, void* d_ws, size_t ws_size,
                              hipStream_t stream) {
    const float* inputs = (const float*)d_in[0];
    const float* W      = (const float*)d_in[1];
    float* out = (float*)d_out;
    float* ws  = (float*)d_ws;
    float* inT   = ws + OFF_INT;
    float* cT    = ws + OFF_CT;
    float* bT    = ws + OFF_BT;
    float* spart = ws + OFF_SPART;
    float* outT  = ws + OFF_OUTT;

    k_transpose<<<I_, 256, 0, stream>>>(inputs, inT);
    // r = 0 (c uniform = 1/N since b=0)
    k_sweep<1><<<dim3(CH_, N_), 256, 0, stream>>>(W, inT, cT, spart);
    k_reduce<0><<<256, 256, 0, stream>>>(spart, outT, out);
    k_update<1><<<dim3(CH_, N_), 256, 0, stream>>>(W, inT, outT, bT);
    k_softmax<<<I_ / 4, 256, 0, stream>>>(bT, cT);
    // r = 1
    k_sweep<0><<<dim3(CH_, N_), 256, 0, stream>>>(W, inT, cT, spart);
    k_reduce<0><<<256, 256, 0, stream>>>(spart, outT, out);
    k_update<0><<<dim3(CH_, N_), 256, 0, stream>>>(W, inT, outT, bT);
    k_softmax<<<I_ / 4, 256, 0, stream>>>(bT, cT);
    // r = 2
    k_sweep<0><<<dim3(CH_, N_), 256, 0, stream>>>(W, inT, cT, spart);
    k_reduce<1><<<256, 256, 0, stream>>>(spart, outT, out);
}

// Round 5
// 1344.978 us; speedup vs baseline: 1.8628x; 1.0047x over previous
//
#include <hip/hip_runtime.h>
#include <math.h>

#define B_ 64
#define I_ 2048
#define K_ 16
#define N_ 32
#define D_ 32
#define CH_ 32      // i-chunks of 64 i each
#define SUB_ 16     // i per LDS staging sub-chunk (32 KB)

#define AS1 __attribute__((address_space(1)))
#define AS3 __attribute__((address_space(3)))

// ws offsets (floats)
#define OFF_INT   0u           // inT   [I][K][B]     2097152
#define OFF_CT    2097152u     // cT    [N][I][B]     4194304
#define OFF_BT    6291456u     // bT    [N][I][B]     4194304
#define OFF_SPART 10485760u    // spart [N][CH][B][D] 2097152
#define OFF_OUTT  12582912u    // outT  [N][D][B]     65536
// total 12648448 floats = 48.25 MB

// ---------------- transpose inputs[b][i][k] -> inT[i][k][b] ----------------
__global__ __launch_bounds__(256) void k_transpose(const float* __restrict__ in,
                                                   float* __restrict__ inT) {
    __shared__ float lds[B_][K_ + 1];
    const int i = blockIdx.x;
    const int t = threadIdx.x;
    const int b = t >> 2, kq = t & 3;
    const float4 v = *(const float4*)(in + ((size_t)b * I_ + i) * K_ + kq * 4);
    lds[b][kq * 4 + 0] = v.x; lds[b][kq * 4 + 1] = v.y;
    lds[b][kq * 4 + 2] = v.z; lds[b][kq * 4 + 3] = v.w;
    __syncthreads();
#pragma unroll
    for (int q = 0; q < 4; ++q) {
        const int j = t + q * 256;          // j = k*64 + b
        const int k = j >> 6, bb = j & 63;
        inT[(size_t)i * (K_ * B_) + j] = lds[bb][k];
    }
}

#define DOT16(xreg, w0, w1, w2, w3) \
    (xreg[0]*w0.x + xreg[1]*w0.y + xreg[2]*w0.z + xreg[3]*w0.w + \
     xreg[4]*w1.x + xreg[5]*w1.y + xreg[6]*w1.z + xreg[7]*w1.w + \
     xreg[8]*w2.x + xreg[9]*w2.y + xreg[10]*w2.z + xreg[11]*w2.w + \
     xreg[12]*w3.x + xreg[13]*w3.y + xreg[14]*w3.z + xreg[15]*w3.w)

// stage SUB_*512 floats (2048 float4) direct global->LDS, no VGPR round-trip.
// wave-uniform LDS base (w*64 + q*256 float4s); HW adds lane*16B.
__device__ __forceinline__ void stage_w_async(const float* __restrict__ src,
                                              float* lds_dst, int w, int lane) {
    const float4* s4 = (const float4*)src;
    float4* d4 = (float4*)lds_dst;
#pragma unroll
    for (int q = 0; q < 8; ++q) {
        __builtin_amdgcn_global_load_lds(
            (const AS1 void*)(const void*)(s4 + q * 256 + w * 64 + lane),
            (AS3 void*)(void*)(d4 + q * 256 + w * 64),
            16, 0, 0);
    }
}

// ---------------- s-sweep: spart[n][ch][b][d] = sum_{i in chunk} c * u_hat --------
template<int UNIFORM>
__global__ __launch_bounds__(256, 2) void k_sweep(const float* __restrict__ W,
                                                  const float* __restrict__ inT,
                                                  const float* __restrict__ cT,
                                                  float* __restrict__ spart) {
    __shared__ __align__(16) float smem[4 * B_ * (D_ + 1)];   // 8448 f >= 8192 stage
    const int n = blockIdx.y, ch = blockIdx.x;
    const int t = threadIdx.x, w = t >> 6, lane = t & 63;   // lane = b

    float acc[D_];
#pragma unroll
    for (int d = 0; d < D_; ++d) acc[d] = 0.f;

    const float* wg = W + (size_t)(n * I_ + ch * 64) * (D_ * K_);

    for (int sc = 0; sc < 4; ++sc) {
        if (sc) __syncthreads();           // prior compute done before LDS overwrite
        stage_w_async(wg + sc * (SUB_ * 512), smem, w, lane);
        __syncthreads();                   // drains vmcnt -> tile resident

#pragma unroll
        for (int q = 0; q < 4; ++q) {
            const int il = w * 4 + q;                 // row in sub-chunk
            const int i  = ch * 64 + sc * SUB_ + il;
            const float c = UNIFORM ? (1.0f / N_)
                                    : cT[((size_t)n * I_ + i) * B_ + lane];
            const float* xp = inT + (size_t)i * (K_ * B_) + lane;
            float xc[K_];
#pragma unroll
            for (int k = 0; k < K_; ++k) xc[k] = c * xp[k * B_];
            const float* wl = smem + il * 512;
#pragma unroll
            for (int d = 0; d < D_; ++d) {
                const float4* w4 = (const float4*)(wl + d * K_);
                const float4 w0 = w4[0], w1 = w4[1], w2 = w4[2], w3 = w4[3];
                acc[d] += DOT16(xc, w0, w1, w2, w3);
            }
        }
    }

    __syncthreads();
    float (*red)[B_][D_ + 1] = (float (*)[B_][D_ + 1])smem;
#pragma unroll
    for (int d = 0; d < D_; ++d) red[w][lane][d] = acc[d];
    __syncthreads();
#pragma unroll
    for (int q = 0; q < 8; ++q) {
        const int j = t + q * 256;                    // j = b*32 + d
        const int b = j >> 5, d = j & 31;
        const float s = red[0][b][d] + red[1][b][d] + red[2][b][d] + red[3][b][d];
        spart[((size_t)n * CH_ + ch) * (B_ * D_) + j] = s;
    }
}

// ---------------- reduce partials + squash ----------------
template<int FINAL>
__global__ __launch_bounds__(256) void k_reduce(const float* __restrict__ spart,
                                                float* __restrict__ outT,
                                                float* __restrict__ out) {
    const int gt = blockIdx.x * 256 + threadIdx.x;   // N*B*D threads
    const int n = gt >> 11;
    const int rem = gt & 2047;                        // b*32 + d
    const int b = rem >> 5, d = rem & 31;
    const float* sp = spart + (size_t)n * (CH_ * B_ * D_) + rem;
    float s = 0.f;
#pragma unroll 8
    for (int p = 0; p < CH_; ++p) s += sp[p * (B_ * D_)];

    float sq = s * s;
#pragma unroll
    for (int off = 16; off >= 1; off >>= 1) sq += __shfl_xor(sq, off, 64);
    const float scale = sq / ((1.0f + sq) * sqrtf(sq + 1e-7f));
    const float o = scale * s;
    if (FINAL) {
        out[((size_t)b * N_ + n) * D_ + d] = o;       // [B][N][D]
    } else {
        outT[((size_t)n * D_ + d) * B_ + b] = o;      // [N][D][B]
    }
}

// ---------------- logits: bT[n][i][b] (+)= sum_d out*u_hat ----------------
template<int FIRST>
__global__ __launch_bounds__(256, 2) void k_update(const float* __restrict__ W,
                                                   const float* __restrict__ inT,
                                                   const float* __restrict__ outT,
                                                   float* __restrict__ bT) {
    __shared__ __align__(16) float smem[SUB_ * 512];
    const int n = blockIdx.y, ch = blockIdx.x;
    const int t = threadIdx.x, w = t >> 6, lane = t & 63;   // lane = b

    float o[D_];
#pragma unroll
    for (int d = 0; d < D_; ++d) o[d] = outT[(size_t)n * (D_ * B_) + d * B_ + lane];

    const float* wg = W + (size_t)(n * I_ + ch * 64) * (D_ * K_);

    for (int sc = 0; sc < 4; ++sc) {
        if (sc) __syncthreads();
        stage_w_async(wg + sc * (SUB_ * 512), smem, w, lane);
        __syncthreads();

#pragma unroll
        for (int q = 0; q < 4; ++q) {
            const int il = w * 4 + q;
            const int i  = ch * 64 + sc * SUB_ + il;
            const float* xp = inT + (size_t)i * (K_ * B_) + lane;
            float x[K_];
#pragma unroll
            for (int k = 0; k < K_; ++k) x[k] = xp[k * B_];
            const float* wl = smem + il * 512;
            float g = 0.f;
#pragma unroll
            for (int d = 0; d < D_; ++d) {
                const float4* w4 = (const float4*)(wl + d * K_);
                const float4 w0 = w4[0], w1 = w4[1], w2 = w4[2], w3 = w4[3];
                const float u = DOT16(x, w0, w1, w2, w3);
                g = fmaf(o[d], u, g);
            }
            const size_t bi = ((size_t)n * I_ + i) * B_ + lane;
            bT[bi] = FIRST ? g : (bT[bi] + g);
        }
    }
}

// ---------------- softmax over n: cT[n][i][b] = softmax_n(bT) ----------------
__global__ __launch_bounds__(256) void k_softmax(const float* __restrict__ bT,
                                                 float* __restrict__ cT) {
    const int t = threadIdx.x, w = t >> 6, lane = t & 63;
    const int i = blockIdx.x * 4 + w;
    float v[N_];
#pragma unroll
    for (int n = 0; n < N_; ++n) v[n] = bT[((size_t)n * I_ + i) * B_ + lane];
    float m = v[0];
#pragma unroll
    for (int n = 1; n < N_; ++n) m = fmaxf(m, v[n]);
    float sum = 0.f;
#pragma unroll
    for (int n = 0; n < N_; ++n) { v[n] = __expf(v[n] - m); sum += v[n]; }
    const float inv = 1.0f / sum;
#pragma unroll
    for (int n = 0; n < N_; ++n)
        cT[((size_t)n * I_ + i) * B_ + lane] = v[n] * inv;
}

extern "C" void kernel_launch(void* const* d_in, const int* in_sizes, int n_in,
                              void* d_out, int out_size, void* d_ws, size_t ws_size,
                              hipStream_t stream) {
    const float* inputs = (const float*)d_in[0];
    const float* W      = (const float*)d_in[1];
    float* out = (float*)d_out;
    float* ws  = (float*)d_ws;
    float* inT   = ws + OFF_INT;
    float* cT    = ws + OFF_CT;
    float* bT    = ws + OFF_BT;
    float* spart = ws + OFF_SPART;
    float* outT  = ws + OFF_OUTT;

    k_transpose<<<I_, 256, 0, stream>>>(inputs, inT);
    // r = 0 (c uniform = 1/N since b=0)
    k_sweep<1><<<dim3(CH_, N_), 256, 0, stream>>>(W, inT, cT, spart);
    k_reduce<0><<<256, 256, 0, stream>>>(spart, outT, out);
    k_update<1><<<dim3(CH_, N_), 256, 0, stream>>>(W, inT, outT, bT);
    k_softmax<<<I_ / 4, 256, 0, stream>>>(bT, cT);
    // r = 1
    k_sweep<0><<<dim3(CH_, N_), 256, 0, stream>>>(W, inT, cT, spart);
    k_reduce<0><<<256, 256, 0, stream>>>(spart, outT, out);
    k_update<0><<<dim3(CH_, N_), 256, 0, stream>>>(W, inT, outT, bT);
    k_softmax<<<I_ / 4, 256, 0, stream>>>(bT, cT);
    // r = 2
    k_sweep<0><<<dim3(CH_, N_), 256, 0, stream>>>(W, inT, cT, spart);
    k_reduce<1><<<256, 256, 0, stream>>>(spart, outT, out);
}

// Round 6
// 746.048 us; speedup vs baseline: 3.3582x; 1.8028x over previous
//
#include <hip/hip_runtime.h>
#include <math.h>

#define B_ 64
#define I_ 2048
#define K_ 16
#define N_ 32
#define D_ 32
#define CH_ 32      // i-chunks of 64 i each
#define SUB_ 16     // i per LDS staging sub-chunk (32 KB)

#define AS1 __attribute__((address_space(1)))
#define AS3 __attribute__((address_space(3)))

// ws offsets (floats)
#define OFF_INT   0u           // inT   [I][K][B]     2097152
#define OFF_CT    2097152u     // cT    [N][I][B]     4194304
#define OFF_BT    6291456u     // bT    [N][I][B]     4194304
#define OFF_SPART 10485760u    // spart [N][CH][B][D] 2097152
#define OFF_OUTT  12582912u    // outT  [N][D][B]     65536
// total 12648448 floats = 48.25 MB

// ---------------- transpose inputs[b][i][k] -> inT[i][k][b] ----------------
__global__ __launch_bounds__(256) void k_transpose(const float* __restrict__ in,
                                                   float* __restrict__ inT) {
    __shared__ float lds[B_][K_ + 1];
    const int i = blockIdx.x;
    const int t = threadIdx.x;
    const int b = t >> 2, kq = t & 3;
    const float4 v = *(const float4*)(in + ((size_t)b * I_ + i) * K_ + kq * 4);
    lds[b][kq * 4 + 0] = v.x; lds[b][kq * 4 + 1] = v.y;
    lds[b][kq * 4 + 2] = v.z; lds[b][kq * 4 + 3] = v.w;
    __syncthreads();
#pragma unroll
    for (int q = 0; q < 4; ++q) {
        const int j = t + q * 256;          // j = k*64 + b
        const int k = j >> 6, bb = j & 63;
        inT[(size_t)i * (K_ * B_) + j] = lds[bb][k];
    }
}

#define DOT16(xreg, w0, w1, w2, w3) \
    (xreg[0]*w0.x + xreg[1]*w0.y + xreg[2]*w0.z + xreg[3]*w0.w + \
     xreg[4]*w1.x + xreg[5]*w1.y + xreg[6]*w1.z + xreg[7]*w1.w + \
     xreg[8]*w2.x + xreg[9]*w2.y + xreg[10]*w2.z + xreg[11]*w2.w + \
     xreg[12]*w3.x + xreg[13]*w3.y + xreg[14]*w3.z + xreg[15]*w3.w)

// stage SUB_*512 floats (2048 float4) direct global->LDS with 512 threads.
__device__ __forceinline__ void stage_w_512(const float* __restrict__ src,
                                            float* lds_dst, int w, int lane) {
    const float4* s4 = (const float4*)src;
    float4* d4 = (float4*)lds_dst;
#pragma unroll
    for (int q = 0; q < 4; ++q) {
        __builtin_amdgcn_global_load_lds(
            (const AS1 void*)(const void*)(s4 + q * 512 + w * 64 + lane),
            (AS3 void*)(void*)(d4 + q * 512 + w * 64),
            16, 0, 0);
    }
}

// stage with 256 threads (k_update)
__device__ __forceinline__ void stage_w_256(const float* __restrict__ src,
                                            float* lds_dst, int w, int lane) {
    const float4* s4 = (const float4*)src;
    float4* d4 = (float4*)lds_dst;
#pragma unroll
    for (int q = 0; q < 8; ++q) {
        __builtin_amdgcn_global_load_lds(
            (const AS1 void*)(const void*)(s4 + q * 256 + w * 64 + lane),
            (AS3 void*)(void*)(d4 + q * 256 + w * 64),
            16, 0, 0);
    }
}

// ---------------- s-sweep: 512 thr, wave w: d-half (w&1), i-group (w>>1) --------
// acc[16] per thread keeps live regs < 128 (no scratch spill).
template<int UNIFORM>
__global__ __launch_bounds__(512, 4) void k_sweep(const float* __restrict__ W,
                                                  const float* __restrict__ inT,
                                                  const float* __restrict__ cT,
                                                  float* __restrict__ spart) {
    __shared__ __align__(16) float smem[8 * B_ * 17];   // 8704 f: stage 8192 / red 8704
    const int n = blockIdx.y, ch = blockIdx.x;
    const int t = threadIdx.x, w = t >> 6, lane = t & 63;   // lane = b
    const int h = w & 1;            // d-half
    const int g = w >> 1;           // i-group (4 i per sc)

    float acc[16];
#pragma unroll
    for (int d = 0; d < 16; ++d) acc[d] = 0.f;

    const float* wg = W + (size_t)(n * I_ + ch * 64) * (D_ * K_);

    for (int sc = 0; sc < 4; ++sc) {
        if (sc) __syncthreads();
        stage_w_512(wg + sc * (SUB_ * 512), smem, w, lane);
        __syncthreads();

#pragma unroll
        for (int q = 0; q < 4; ++q) {
            const int il = g * 4 + q;                 // row in sub-chunk
            const int i  = ch * 64 + sc * SUB_ + il;
            const float c = UNIFORM ? (1.0f / N_)
                                    : cT[((size_t)n * I_ + i) * B_ + lane];
            const float* xp = inT + (size_t)i * (K_ * B_) + lane;
            float xc[K_];
#pragma unroll
            for (int k = 0; k < K_; ++k) xc[k] = c * xp[k * B_];
            const float* wl = smem + il * 512 + h * 256;   // 16 d of this half
#pragma unroll
            for (int d = 0; d < 16; ++d) {
                const float4* w4 = (const float4*)(wl + d * K_);
                const float4 w0 = w4[0], w1 = w4[1], w2 = w4[2], w3 = w4[3];
                acc[d] += DOT16(xc, w0, w1, w2, w3);
            }
        }
    }

    // cross-wave reduce over the 4 i-groups, per d-half
    __syncthreads();
#pragma unroll
    for (int d = 0; d < 16; ++d) smem[(w * B_ + lane) * 17 + d] = acc[d];
    __syncthreads();
#pragma unroll
    for (int q = 0; q < 4; ++q) {
        const int j = q * 512 + t;                    // j = b*32 + d  (2048 total)
        const int b = j >> 5, d = j & 31;
        const int hh = d >> 4, dd = d & 15;
        float s = 0.f;
#pragma unroll
        for (int g2 = 0; g2 < 4; ++g2)
            s += smem[((g2 * 2 + hh) * B_ + b) * 17 + dd];
        spart[((size_t)n * CH_ + ch) * (B_ * D_) + j] = s;
    }
}

// ---------------- reduce partials + squash ----------------
template<int FINAL>
__global__ __launch_bounds__(256) void k_reduce(const float* __restrict__ spart,
                                                float* __restrict__ outT,
                                                float* __restrict__ out) {
    const int gt = blockIdx.x * 256 + threadIdx.x;   // N*B*D threads
    const int n = gt >> 11;
    const int rem = gt & 2047;                        // b*32 + d
    const int b = rem >> 5, d = rem & 31;
    const float* sp = spart + (size_t)n * (CH_ * B_ * D_) + rem;
    float s = 0.f;
#pragma unroll 8
    for (int p = 0; p < CH_; ++p) s += sp[p * (B_ * D_)];

    float sq = s * s;
#pragma unroll
    for (int off = 16; off >= 1; off >>= 1) sq += __shfl_xor(sq, off, 64);
    const float scale = sq / ((1.0f + sq) * sqrtf(sq + 1e-7f));
    const float o = scale * s;
    if (FINAL) {
        out[((size_t)b * N_ + n) * D_ + d] = o;       // [B][N][D]
    } else {
        outT[((size_t)n * D_ + d) * B_ + b] = o;      // [N][D][B]
    }
}

// ---------------- logits: bT[n][i][b] (+)= sum_d out*u_hat ----------------
template<int FIRST>
__global__ __launch_bounds__(256, 2) void k_update(const float* __restrict__ W,
                                                   const float* __restrict__ inT,
                                                   const float* __restrict__ outT,
                                                   float* __restrict__ bT) {
    __shared__ __align__(16) float smem[SUB_ * 512];
    const int n = blockIdx.y, ch = blockIdx.x;
    const int t = threadIdx.x, w = t >> 6, lane = t & 63;   // lane = b

    float o[D_];
#pragma unroll
    for (int d = 0; d < D_; ++d) o[d] = outT[(size_t)n * (D_ * B_) + d * B_ + lane];

    const float* wg = W + (size_t)(n * I_ + ch * 64) * (D_ * K_);

    for (int sc = 0; sc < 4; ++sc) {
        if (sc) __syncthreads();
        stage_w_256(wg + sc * (SUB_ * 512), smem, w, lane);
        __syncthreads();

#pragma unroll
        for (int q = 0; q < 4; ++q) {
            const int il = w * 4 + q;
            const int i  = ch * 64 + sc * SUB_ + il;
            const float* xp = inT + (size_t)i * (K_ * B_) + lane;
            float x[K_];
#pragma unroll
            for (int k = 0; k < K_; ++k) x[k] = xp[k * B_];
            const float* wl = smem + il * 512;
            float g = 0.f;
#pragma unroll
            for (int d = 0; d < D_; ++d) {
                const float4* w4 = (const float4*)(wl + d * K_);
                const float4 w0 = w4[0], w1 = w4[1], w2 = w4[2], w3 = w4[3];
                const float u = DOT16(x, w0, w1, w2, w3);
                g = fmaf(o[d], u, g);
            }
            const size_t bi = ((size_t)n * I_ + i) * B_ + lane;
            bT[bi] = FIRST ? g : (bT[bi] + g);
        }
    }
}

// ---------------- softmax over n: cT[n][i][b] = softmax_n(bT) ----------------
__global__ __launch_bounds__(256) void k_softmax(const float* __restrict__ bT,
                                                 float* __restrict__ cT) {
    const int t = threadIdx.x, w = t >> 6, lane = t & 63;
    const int i = blockIdx.x * 4 + w;
    float v[N_];
#pragma unroll
    for (int n = 0; n < N_; ++n) v[n] = bT[((size_t)n * I_ + i) * B_ + lane];
    float m = v[0];
#pragma unroll
    for (int n = 1; n < N_; ++n) m = fmaxf(m, v[n]);
    float sum = 0.f;
#pragma unroll
    for (int n = 0; n < N_; ++n) { v[n] = __expf(v[n] - m); sum += v[n]; }
    const float inv = 1.0f / sum;
#pragma unroll
    for (int n = 0; n < N_; ++n)
        cT[((size_t)n * I_ + i) * B_ + lane] = v[n] * inv;
}

extern "C" void kernel_launch(void* const* d_in, const int* in_sizes, int n_in,
                              void* d_out, int out_size, void* d_ws, size_t ws_size,
                              hipStream_t stream) {
    const float* inputs = (const float*)d_in[0];
    const float* W      = (const float*)d_in[1];
    float* out = (float*)d_out;
    float* ws  = (float*)d_ws;
    float* inT   = ws + OFF_INT;
    float* cT    = ws + OFF_CT;
    float* bT    = ws + OFF_BT;
    float* spart = ws + OFF_SPART;
    float* outT  = ws + OFF_OUTT;

    k_transpose<<<I_, 256, 0, stream>>>(inputs, inT);
    // r = 0 (c uniform = 1/N since b=0)
    k_sweep<1><<<dim3(CH_, N_), 512, 0, stream>>>(W, inT, cT, spart);
    k_reduce<0><<<256, 256, 0, stream>>>(spart, outT, out);
    k_update<1><<<dim3(CH_, N_), 256, 0, stream>>>(W, inT, outT, bT);
    k_softmax<<<I_ / 4, 256, 0, stream>>>(bT, cT);
    // r = 1
    k_sweep<0><<<dim3(CH_, N_), 512, 0, stream>>>(W, inT, cT, spart);
    k_reduce<0><<<256, 256, 0, stream>>>(spart, outT, out);
    k_update<0><<<dim3(CH_, N_), 256, 0, stream>>>(W, inT, outT, bT);
    k_softmax<<<I_ / 4, 256, 0, stream>>>(bT, cT);
    // r = 2
    k_sweep<0><<<dim3(CH_, N_), 512, 0, stream>>>(W, inT, cT, spart);
    k_reduce<1><<<256, 256, 0, stream>>>(spart, outT, out);
}

// Round 7
// 641.221 us; speedup vs baseline: 3.9072x; 1.1635x over previous
//
#include <hip/hip_runtime.h>
#include <math.h>

#define B_ 64
#define I_ 2048
#define K_ 16
#define N_ 32
#define D_ 32
#define CH_ 32      // i-chunks of 64 i each
#define SUB_ 16     // i per LDS staging sub-chunk (32 KB)

#define AS1 __attribute__((address_space(1)))
#define AS3 __attribute__((address_space(3)))

// ws offsets (floats)
#define OFF_INT   0u           // inT   [I][K][B]     2097152
#define OFF_CT    2097152u     // cT    [N][I][B]     4194304
#define OFF_BT    6291456u     // bT    [N][I][B]     4194304
#define OFF_SPART 10485760u    // spart [N][CH][B][D] 2097152
#define OFF_OUTT  12582912u    // outT  [N][D][B]     65536
// total 12648448 floats = 48.25 MB

// ---------------- transpose inputs[b][i][k] -> inT[i][k][b] ----------------
__global__ __launch_bounds__(256) void k_transpose(const float* __restrict__ in,
                                                   float* __restrict__ inT) {
    __shared__ float lds[B_][K_ + 1];
    const int i = blockIdx.x;
    const int t = threadIdx.x;
    const int b = t >> 2, kq = t & 3;
    const float4 v = *(const float4*)(in + ((size_t)b * I_ + i) * K_ + kq * 4);
    lds[b][kq * 4 + 0] = v.x; lds[b][kq * 4 + 1] = v.y;
    lds[b][kq * 4 + 2] = v.z; lds[b][kq * 4 + 3] = v.w;
    __syncthreads();
#pragma unroll
    for (int q = 0; q < 4; ++q) {
        const int j = t + q * 256;          // j = k*64 + b
        const int k = j >> 6, bb = j & 63;
        inT[(size_t)i * (K_ * B_) + j] = lds[bb][k];
    }
}

#define DOT16(xreg, w0, w1, w2, w3) \
    (xreg[0]*w0.x + xreg[1]*w0.y + xreg[2]*w0.z + xreg[3]*w0.w + \
     xreg[4]*w1.x + xreg[5]*w1.y + xreg[6]*w1.z + xreg[7]*w1.w + \
     xreg[8]*w2.x + xreg[9]*w2.y + xreg[10]*w2.z + xreg[11]*w2.w + \
     xreg[12]*w3.x + xreg[13]*w3.y + xreg[14]*w3.z + xreg[15]*w3.w)

// stage SUB_*512 floats (2048 float4) direct global->LDS with 512 threads.
__device__ __forceinline__ void stage_w_512(const float* __restrict__ src,
                                            float* lds_dst, int w, int lane) {
    const float4* s4 = (const float4*)src;
    float4* d4 = (float4*)lds_dst;
#pragma unroll
    for (int q = 0; q < 4; ++q) {
        __builtin_amdgcn_global_load_lds(
            (const AS1 void*)(const void*)(s4 + q * 512 + w * 64 + lane),
            (AS3 void*)(void*)(d4 + q * 512 + w * 64),
            16, 0, 0);
    }
}

// stage with 256 threads (k_update)
__device__ __forceinline__ void stage_w_256(const float* __restrict__ src,
                                            float* lds_dst, int w, int lane) {
    const float4* s4 = (const float4*)src;
    float4* d4 = (float4*)lds_dst;
#pragma unroll
    for (int q = 0; q < 8; ++q) {
        __builtin_amdgcn_global_load_lds(
            (const AS1 void*)(const void*)(s4 + q * 256 + w * 64 + lane),
            (AS3 void*)(void*)(d4 + q * 256 + w * 64),
            16, 0, 0);
    }
}

// ---------------- s-sweep: 512 thr, wave w: d-half (w&1), i-group (w>>1) --------
// acc[16] per thread; __launch_bounds__(512,2) -> VGPR cap 128 (2 blk * 16 waves/CU)
template<int UNIFORM>
__global__ __launch_bounds__(512, 2) void k_sweep(const float* __restrict__ W,
                                                  const float* __restrict__ inT,
                                                  const float* __restrict__ cT,
                                                  float* __restrict__ spart) {
    __shared__ __align__(16) float smem[8 * B_ * 17];   // 8704 f: stage 8192 / red 8704
    const int n = blockIdx.y, ch = blockIdx.x;
    const int t = threadIdx.x, w = t >> 6, lane = t & 63;   // lane = b
    const int h = w & 1;            // d-half
    const int g = w >> 1;           // i-group (4 i per sc)

    float acc[16];
#pragma unroll
    for (int d = 0; d < 16; ++d) acc[d] = 0.f;

    const float* wg = W + (size_t)(n * I_ + ch * 64) * (D_ * K_);

    for (int sc = 0; sc < 4; ++sc) {
        if (sc) __syncthreads();
        stage_w_512(wg + sc * (SUB_ * 512), smem, w, lane);
        __syncthreads();

#pragma unroll
        for (int q = 0; q < 4; ++q) {
            const int il = g * 4 + q;                 // row in sub-chunk
            const int i  = ch * 64 + sc * SUB_ + il;
            const float c = UNIFORM ? (1.0f / N_)
                                    : cT[((size_t)n * I_ + i) * B_ + lane];
            const float* xp = inT + (size_t)i * (K_ * B_) + lane;
            float xc[K_];
#pragma unroll
            for (int k = 0; k < K_; ++k) xc[k] = c * xp[k * B_];
            const float* wl = smem + il * 512 + h * 256;   // 16 d of this half
#pragma unroll
            for (int d = 0; d < 16; ++d) {
                const float4* w4 = (const float4*)(wl + d * K_);
                const float4 w0 = w4[0], w1 = w4[1], w2 = w4[2], w3 = w4[3];
                acc[d] += DOT16(xc, w0, w1, w2, w3);
            }
        }
    }

    // cross-wave reduce over the 4 i-groups, per d-half
    __syncthreads();
#pragma unroll
    for (int d = 0; d < 16; ++d) smem[(w * B_ + lane) * 17 + d] = acc[d];
    __syncthreads();
#pragma unroll
    for (int q = 0; q < 4; ++q) {
        const int j = q * 512 + t;                    // j = b*32 + d  (2048 total)
        const int b = j >> 5, d = j & 31;
        const int hh = d >> 4, dd = d & 15;
        float s = 0.f;
#pragma unroll
        for (int g2 = 0; g2 < 4; ++g2)
            s += smem[((g2 * 2 + hh) * B_ + b) * 17 + dd];
        spart[((size_t)n * CH_ + ch) * (B_ * D_) + j] = s;
    }
}

// ---------------- reduce partials + squash ----------------
template<int FINAL>
__global__ __launch_bounds__(256) void k_reduce(const float* __restrict__ spart,
                                                float* __restrict__ outT,
                                                float* __restrict__ out) {
    const int gt = blockIdx.x * 256 + threadIdx.x;   // N*B*D threads
    const int n = gt >> 11;
    const int rem = gt & 2047;                        // b*32 + d
    const int b = rem >> 5, d = rem & 31;
    const float* sp = spart + (size_t)n * (CH_ * B_ * D_) + rem;
    float s = 0.f;
#pragma unroll 8
    for (int p = 0; p < CH_; ++p) s += sp[p * (B_ * D_)];

    float sq = s * s;
#pragma unroll
    for (int off = 16; off >= 1; off >>= 1) sq += __shfl_xor(sq, off, 64);
    const float scale = sq / ((1.0f + sq) * sqrtf(sq + 1e-7f));
    const float o = scale * s;
    if (FINAL) {
        out[((size_t)b * N_ + n) * D_ + d] = o;       // [B][N][D]
    } else {
        outT[((size_t)n * D_ + d) * B_ + b] = o;      // [N][D][B]
    }
}

// ---------------- logits: bT[n][i][b] (+)= sum_d out*u_hat ----------------
template<int FIRST>
__global__ __launch_bounds__(256, 2) void k_update(const float* __restrict__ W,
                                                   const float* __restrict__ inT,
                                                   const float* __restrict__ outT,
                                                   float* __restrict__ bT) {
    __shared__ __align__(16) float smem[SUB_ * 512];
    const int n = blockIdx.y, ch = blockIdx.x;
    const int t = threadIdx.x, w = t >> 6, lane = t & 63;   // lane = b

    float o[D_];
#pragma unroll
    for (int d = 0; d < D_; ++d) o[d] = outT[(size_t)n * (D_ * B_) + d * B_ + lane];

    const float* wg = W + (size_t)(n * I_ + ch * 64) * (D_ * K_);

    for (int sc = 0; sc < 4; ++sc) {
        if (sc) __syncthreads();
        stage_w_256(wg + sc * (SUB_ * 512), smem, w, lane);
        __syncthreads();

#pragma unroll
        for (int q = 0; q < 4; ++q) {
            const int il = w * 4 + q;
            const int i  = ch * 64 + sc * SUB_ + il;
            const float* xp = inT + (size_t)i * (K_ * B_) + lane;
            float x[K_];
#pragma unroll
            for (int k = 0; k < K_; ++k) x[k] = xp[k * B_];
            const float* wl = smem + il * 512;
            float g = 0.f;
#pragma unroll
            for (int d = 0; d < D_; ++d) {
                const float4* w4 = (const float4*)(wl + d * K_);
                const float4 w0 = w4[0], w1 = w4[1], w2 = w4[2], w3 = w4[3];
                const float u = DOT16(x, w0, w1, w2, w3);
                g = fmaf(o[d], u, g);
            }
            const size_t bi = ((size_t)n * I_ + i) * B_ + lane;
            bT[bi] = FIRST ? g : (bT[bi] + g);
        }
    }
}

// ---------------- softmax over n: cT[n][i][b] = softmax_n(bT) ----------------
__global__ __launch_bounds__(256) void k_softmax(const float* __restrict__ bT,
                                                 float* __restrict__ cT) {
    const int t = threadIdx.x, w = t >> 6, lane = t & 63;
    const int i = blockIdx.x * 4 + w;
    float v[N_];
#pragma unroll
    for (int n = 0; n < N_; ++n) v[n] = bT[((size_t)n * I_ + i) * B_ + lane];
    float m = v[0];
#pragma unroll
    for (int n = 1; n < N_; ++n) m = fmaxf(m, v[n]);
    float sum = 0.f;
#pragma unroll
    for (int n = 0; n < N_; ++n) { v[n] = __expf(v[n] - m); sum += v[n]; }
    const float inv = 1.0f / sum;
#pragma unroll
    for (int n = 0; n < N_; ++n)
        cT[((size_t)n * I_ + i) * B_ + lane] = v[n] * inv;
}

extern "C" void kernel_launch(void* const* d_in, const int* in_sizes, int n_in,
                              void* d_out, int out_size, void* d_ws, size_t ws_size,
                              hipStream_t stream) {
    const float* inputs = (const float*)d_in[0];
    const float* W      = (const float*)d_in[1];
    float* out = (float*)d_out;
    float* ws  = (float*)d_ws;
    float* inT   = ws + OFF_INT;
    float* cT    = ws + OFF_CT;
    float* bT    = ws + OFF_BT;
    float* spart = ws + OFF_SPART;
    float* outT  = ws + OFF_OUTT;

    k_transpose<<<I_, 256, 0, stream>>>(inputs, inT);
    // r = 0 (c uniform = 1/N since b=0)
    k_sweep<1><<<dim3(CH_, N_), 512, 0, stream>>>(W, inT, cT, spart);
    k_reduce<0><<<256, 256, 0, stream>>>(spart, outT, out);
    k_update<1><<<dim3(CH_, N_), 256, 0, stream>>>(W, inT, outT, bT);
    k_softmax<<<I_ / 4, 256, 0, stream>>>(bT, cT);
    // r = 1
    k_sweep<0><<<dim3(CH_, N_), 512, 0, stream>>>(W, inT, cT, spart);
    k_reduce<0><<<256, 256, 0, stream>>>(spart, outT, out);
    k_update<0><<<dim3(CH_, N_), 256, 0, stream>>>(W, inT, outT, bT);
    k_softmax<<<I_ / 4, 256, 0, stream>>>(bT, cT);
    // r = 2
    k_sweep<0><<<dim3(CH_, N_), 512, 0, stream>>>(W, inT, cT, spart);
    k_reduce<1><<<256, 256, 0, stream>>>(spart, outT, out);
}

// Round 8
// 296.357 us; speedup vs baseline: 8.4540x; 2.1637x over previous
//
#include <hip/hip_runtime.h>
#include <hip/hip_bf16.h>
#include <math.h>

#define B_ 64
#define I_ 2048
#define K_ 16
#define N_ 32
#define D_ 32
#define CH_ 32      // i-chunks for k_update (64 i each)
#define SCH_ 16     // i-chunks for mfma sweep (128 i each)
#define SUB_ 16     // i per LDS staging sub-chunk in k_update

#define AS1 __attribute__((address_space(1)))
#define AS3 __attribute__((address_space(3)))

typedef __attribute__((ext_vector_type(8))) short short8_t;   // 8 bf16
typedef __attribute__((ext_vector_type(4))) float f32x4_t;

// ws offsets (floats)
#define OFF_INT   0u           // inT   [I][K][B]        2097152
#define OFF_CT    2097152u     // cT    [N][I][B]        4194304
#define OFF_BT    6291456u     // bT    [N][I][B]        4194304
#define OFF_SPART 10485760u    // spart [N][SCH][B][D]   1048576
#define OFF_OUTT  11534336u    // outT  [N][D][B]          65536
#define OFF_XFRAG 11599872u    // xfrag [4][1024][64] uint4 (bf16x8) = 1048576 f-slots
// total 12648448 floats = 48.25 MB (same budget as round 1 — known to fit)

// ---------------- helpers ----------------
__device__ __forceinline__ unsigned int pk_bf16(float lo, float hi) {
    union { __hip_bfloat162 h2; unsigned int u; } cv;
    cv.h2 = __float22bfloat162_rn(float2{lo, hi});
    return cv.u;
}

__device__ __forceinline__ short8_t pack8(float4 a, float4 b) {
    union { unsigned int u[4]; short8_t v; } r;
    r.u[0] = pk_bf16(a.x, a.y); r.u[1] = pk_bf16(a.z, a.w);
    r.u[2] = pk_bf16(b.x, b.y); r.u[3] = pk_bf16(b.z, b.w);
    return r.v;
}

// ---------------- transpose inputs[b][i][k] -> inT[i][k][b] (for k_update) ----
__global__ __launch_bounds__(256) void k_transpose(const float* __restrict__ in,
                                                   float* __restrict__ inT) {
    __shared__ float lds[B_][K_ + 1];
    const int i = blockIdx.x;
    const int t = threadIdx.x;
    const int b = t >> 2, kq = t & 3;
    const float4 v = *(const float4*)(in + ((size_t)b * I_ + i) * K_ + kq * 4);
    lds[b][kq * 4 + 0] = v.x; lds[b][kq * 4 + 1] = v.y;
    lds[b][kq * 4 + 2] = v.z; lds[b][kq * 4 + 3] = v.w;
    __syncthreads();
#pragma unroll
    for (int q = 0; q < 4; ++q) {
        const int j = t + q * 256;          // j = k*64 + b
        const int k = j >> 6, bb = j & 63;
        inT[(size_t)i * (K_ * B_) + j] = lds[bb][k];
    }
}

// ---------------- pack inputs into MFMA A-fragment order (bf16) ----------------
// xfrag[m][kk][lane] : 8 bf16 = x[b = m*16+(l&15)][i = 2kk+(g>>1)][k = 8(g&1)..+7]
__global__ __launch_bounds__(256) void k_xfrag(const float* __restrict__ in,
                                               uint4* __restrict__ xfrag) {
    const int tid = blockIdx.x * 256 + threadIdx.x;    // [m][kk][l]
    const int l = tid & 63, kk = (tid >> 6) & 1023, m = tid >> 16;
    const int b = m * 16 + (l & 15), g = l >> 4;
    const int i = 2 * kk + (g >> 1), k0 = 8 * (g & 1);
    const float* src = in + ((size_t)b * I_ + i) * K_ + k0;
    const float4 f0 = *(const float4*)src;
    const float4 f1 = *(const float4*)(src + 4);
    uint4 o;
    o.x = pk_bf16(f0.x, f0.y); o.y = pk_bf16(f0.z, f0.w);
    o.z = pk_bf16(f1.x, f1.y); o.w = pk_bf16(f1.z, f1.w);
    xfrag[tid] = o;
}

// ---------------- MFMA s-sweep ----------------
// Per n: D[b][d] = sum_{i,k} A[b][(i,k)]*W[n,i,d,k], A = c*x (bf16), W gathered
// on the fly (fp32 -> bf16). Block = 512 thr = 8 waves = 4 mtile x 2 kslice.
// Wave owns 16b x 32d (2 n-tiles), 32 kk-steps. UNIFORM: A = raw xfrag,
// the 1/N scale is applied in k_reduce.
template<int UNIFORM>
__global__ __launch_bounds__(512, 2) void k_sweep_mfma(const float* __restrict__ W,
                                                       const uint4* __restrict__ xfrag,
                                                       const float* __restrict__ cT,
                                                       float* __restrict__ spart) {
    __shared__ float red[2][B_][D_ + 1];
    const int n = blockIdx.y, ch = blockIdx.x;
    const int t = threadIdx.x, w = t >> 6, l = t & 63;
    const int m = w >> 1, ks = w & 1;
    const int g = l >> 4;

    f32x4_t acc0 = {0.f, 0.f, 0.f, 0.f};
    f32x4_t acc1 = {0.f, 0.f, 0.f, 0.f};

    const uint4* xf = xfrag + (size_t)m * 65536 + l;           // + kk*64
    const float* wb = W + (size_t)n * (I_ * 512);
    const int wlane = (g >> 1) * 512 + (l & 15) * 16 + (g & 1) * 8;
    const int kk0 = ch * 64 + ks * 32;

    for (int tt = 0; tt < 32; ++tt) {
        const int kk = kk0 + tt;
        // ---- A fragment ----
        union { uint4 q; unsigned int u[4]; } xv;
        xv.q = xf[(size_t)kk * 64];
        union { unsigned int u[4]; short8_t v; } af;
        if (UNIFORM) {
            af.u[0] = xv.u[0]; af.u[1] = xv.u[1];
            af.u[2] = xv.u[2]; af.u[3] = xv.u[3];
        } else {
            const float c = cT[((size_t)n * I_ + 2 * kk + (l >> 5)) * B_
                               + m * 16 + (l & 15)];
#pragma unroll
            for (int p = 0; p < 4; ++p) {
                const unsigned int uu = xv.u[p];
                const float lo = __uint_as_float(uu << 16);
                const float hi = __uint_as_float(uu & 0xffff0000u);
                af.u[p] = pk_bf16(lo * c, hi * c);
            }
        }
        // ---- B fragments (gather W fp32 -> bf16), nt = 0,1 ----
        const float* wp = wb + (size_t)kk * 1024 + wlane;
        const short8_t bf0 = pack8(*(const float4*)wp, *(const float4*)(wp + 4));
        const short8_t bf1 = pack8(*(const float4*)(wp + 256), *(const float4*)(wp + 260));

        acc0 = __builtin_amdgcn_mfma_f32_16x16x32_bf16(af.v, bf0, acc0, 0, 0, 0);
        acc1 = __builtin_amdgcn_mfma_f32_16x16x32_bf16(af.v, bf1, acc1, 0, 0, 0);
    }

    // ---- epilogue: C/D layout col=lane&15, row=(lane>>4)*4+reg (m89) ----
#pragma unroll
    for (int r = 0; r < 4; ++r) {
        const int row = m * 16 + (l >> 4) * 4 + r;
        red[ks][row][(l & 15)]      = acc0[r];
        red[ks][row][16 + (l & 15)] = acc1[r];
    }
    __syncthreads();
#pragma unroll
    for (int q = 0; q < 4; ++q) {
        const int j = q * 512 + t;                  // j = b*32 + d
        const int b = j >> 5, d = j & 31;
        spart[((size_t)n * SCH_ + ch) * (B_ * D_) + j] = red[0][b][d] + red[1][b][d];
    }
}

// ---------------- reduce partials + squash ----------------
template<int FINAL>
__global__ __launch_bounds__(256) void k_reduce(const float* __restrict__ spart,
                                                float* __restrict__ outT,
                                                float* __restrict__ out,
                                                float prescale) {
    const int gt = blockIdx.x * 256 + threadIdx.x;   // N*B*D threads
    const int n = gt >> 11;
    const int rem = gt & 2047;                        // b*32 + d
    const int b = rem >> 5, d = rem & 31;
    const float* sp = spart + (size_t)n * (SCH_ * B_ * D_) + rem;
    float s = 0.f;
#pragma unroll
    for (int p = 0; p < SCH_; ++p) s += sp[p * (B_ * D_)];
    s *= prescale;

    float sq = s * s;
#pragma unroll
    for (int off = 16; off >= 1; off >>= 1) sq += __shfl_xor(sq, off, 64);
    const float scale = sq / ((1.0f + sq) * sqrtf(sq + 1e-7f));
    const float o = scale * s;
    if (FINAL) {
        out[((size_t)b * N_ + n) * D_ + d] = o;       // [B][N][D]
    } else {
        outT[((size_t)n * D_ + d) * B_ + b] = o;      // [N][D][B]
    }
}

// ---------------- stage W tile 256-thread (k_update) ----------------
__device__ __forceinline__ void stage_w_256(const float* __restrict__ src,
                                            float* lds_dst, int w, int lane) {
    const float4* s4 = (const float4*)src;
    float4* d4 = (float4*)lds_dst;
#pragma unroll
    for (int q = 0; q < 8; ++q) {
        __builtin_amdgcn_global_load_lds(
            (const AS1 void*)(const void*)(s4 + q * 256 + w * 64 + lane),
            (AS3 void*)(void*)(d4 + q * 256 + w * 64),
            16, 0, 0);
    }
}

#define DOT16(xreg, w0, w1, w2, w3) \
    (xreg[0]*w0.x + xreg[1]*w0.y + xreg[2]*w0.z + xreg[3]*w0.w + \
     xreg[4]*w1.x + xreg[5]*w1.y + xreg[6]*w1.z + xreg[7]*w1.w + \
     xreg[8]*w2.x + xreg[9]*w2.y + xreg[10]*w2.z + xreg[11]*w2.w + \
     xreg[12]*w3.x + xreg[13]*w3.y + xreg[14]*w3.z + xreg[15]*w3.w)

// ---------------- logits: bT[n][i][b] (+)= sum_d out*u_hat ----------------
template<int FIRST>
__global__ __launch_bounds__(256, 2) void k_update(const float* __restrict__ W,
                                                   const float* __restrict__ inT,
                                                   const float* __restrict__ outT,
                                                   float* __restrict__ bT) {
    __shared__ __align__(16) float smem[SUB_ * 512];
    const int n = blockIdx.y, ch = blockIdx.x;
    const int t = threadIdx.x, w = t >> 6, lane = t & 63;   // lane = b

    float o[D_];
#pragma unroll
    for (int d = 0; d < D_; ++d) o[d] = outT[(size_t)n * (D_ * B_) + d * B_ + lane];

    const float* wg = W + (size_t)(n * I_ + ch * 64) * (D_ * K_);

    for (int sc = 0; sc < 4; ++sc) {
        if (sc) __syncthreads();
        stage_w_256(wg + sc * (SUB_ * 512), smem, w, lane);
        __syncthreads();

#pragma unroll
        for (int q = 0; q < 4; ++q) {
            const int il = w * 4 + q;
            const int i  = ch * 64 + sc * SUB_ + il;
            const float* xp = inT + (size_t)i * (K_ * B_) + lane;
            float x[K_];
#pragma unroll
            for (int k = 0; k < K_; ++k) x[k] = xp[k * B_];
            const float* wl = smem + il * 512;
            float gg = 0.f;
#pragma unroll
            for (int d = 0; d < D_; ++d) {
                const float4* w4 = (const float4*)(wl + d * K_);
                const float4 w0 = w4[0], w1 = w4[1], w2 = w4[2], w3 = w4[3];
                const float u = DOT16(x, w0, w1, w2, w3);
                gg = fmaf(o[d], u, gg);
            }
            const size_t bi = ((size_t)n * I_ + i) * B_ + lane;
            bT[bi] = FIRST ? gg : (bT[bi] + gg);
        }
    }
}

// ---------------- softmax over n: cT[n][i][b] = softmax_n(bT) ----------------
__global__ __launch_bounds__(256) void k_softmax(const float* __restrict__ bT,
                                                 float* __restrict__ cT) {
    const int t = threadIdx.x, w = t >> 6, lane = t & 63;
    const int i = blockIdx.x * 4 + w;
    float v[N_];
#pragma unroll
    for (int n = 0; n < N_; ++n) v[n] = bT[((size_t)n * I_ + i) * B_ + lane];
    float m = v[0];
#pragma unroll
    for (int n = 1; n < N_; ++n) m = fmaxf(m, v[n]);
    float sum = 0.f;
#pragma unroll
    for (int n = 0; n < N_; ++n) { v[n] = __expf(v[n] - m); sum += v[n]; }
    const float inv = 1.0f / sum;
#pragma unroll
    for (int n = 0; n < N_; ++n)
        cT[((size_t)n * I_ + i) * B_ + lane] = v[n] * inv;
}

extern "C" void kernel_launch(void* const* d_in, const int* in_sizes, int n_in,
                              void* d_out, int out_size, void* d_ws, size_t ws_size,
                              hipStream_t stream) {
    const float* inputs = (const float*)d_in[0];
    const float* W      = (const float*)d_in[1];
    float* out = (float*)d_out;
    float* ws  = (float*)d_ws;
    float* inT   = ws + OFF_INT;
    float* cT    = ws + OFF_CT;
    float* bT    = ws + OFF_BT;
    float* spart = ws + OFF_SPART;
    float* outT  = ws + OFF_OUTT;
    uint4* xfrag = (uint4*)(ws + OFF_XFRAG);

    k_transpose<<<I_, 256, 0, stream>>>(inputs, inT);
    k_xfrag<<<1024, 256, 0, stream>>>(inputs, xfrag);
    // r = 0 (uniform c = 1/N, applied as prescale in k_reduce)
    k_sweep_mfma<1><<<dim3(SCH_, N_), 512, 0, stream>>>(W, xfrag, cT, spart);
    k_reduce<0><<<256, 256, 0, stream>>>(spart, outT, out, 1.0f / N_);
    k_update<1><<<dim3(CH_, N_), 256, 0, stream>>>(W, inT, outT, bT);
    k_softmax<<<I_ / 4, 256, 0, stream>>>(bT, cT);
    // r = 1
    k_sweep_mfma<0><<<dim3(SCH_, N_), 512, 0, stream>>>(W, xfrag, cT, spart);
    k_reduce<0><<<256, 256, 0, stream>>>(spart, outT, out, 1.0f);
    k_update<0><<<dim3(CH_, N_), 256, 0, stream>>>(W, inT, outT, bT);
    k_softmax<<<I_ / 4, 256, 0, stream>>>(bT, cT);
    // r = 2
    k_sweep_mfma<0><<<dim3(SCH_, N_), 512, 0, stream>>>(W, xfrag, cT, spart);
    k_reduce<1><<<256, 256, 0, stream>>>(spart, outT, out, 1.0f);
}

// Round 9
// 225.311 us; speedup vs baseline: 11.1198x; 1.3153x over previous
//
#include <hip/hip_runtime.h>
#include <hip/hip_bf16.h>
#include <math.h>

#define B_ 64
#define I_ 2048
#define K_ 16
#define N_ 32
#define D_ 32
#define CH_ 32      // i-chunks (64 i each) for update
#define SCH_ 16     // i-chunks for mfma sweep (128 i each)

typedef __attribute__((ext_vector_type(8))) short short8_t;   // 8 bf16
typedef __attribute__((ext_vector_type(4))) float f32x4_t;

// ws offsets (floats)
#define OFF_INT   0u           // inT   [I][K][B]        2097152
#define OFF_CT    2097152u     // cT    [N][I][B]        4194304
#define OFF_BT    6291456u     // bT    [N][I][B]        4194304
#define OFF_SPART 10485760u    // spart [N][SCH][B][D]   1048576
#define OFF_OUTT  11534336u    // outT  [N][D][B]          65536
#define OFF_XFRAG 11599872u    // xfrag [4][1024][64] uint4 = 1048576 f-slots
// total 12648448 floats = 48.25 MB

// ---------------- helpers ----------------
__device__ __forceinline__ unsigned int pk_bf16(float lo, float hi) {
    union { __hip_bfloat162 h2; unsigned int u; } cv;
    cv.h2 = __float22bfloat162_rn(float2{lo, hi});
    return cv.u;
}

__device__ __forceinline__ short8_t pack8(float4 a, float4 b) {
    union { unsigned int u[4]; short8_t v; } r;
    r.u[0] = pk_bf16(a.x, a.y); r.u[1] = pk_bf16(a.z, a.w);
    r.u[2] = pk_bf16(b.x, b.y); r.u[3] = pk_bf16(b.z, b.w);
    return r.v;
}

// ---------------- transpose inputs[b][i][k] -> inT[i][k][b] ----------------
__global__ __launch_bounds__(256) void k_transpose(const float* __restrict__ in,
                                                   float* __restrict__ inT) {
    __shared__ float lds[B_][K_ + 1];
    const int i = blockIdx.x;
    const int t = threadIdx.x;
    const int b = t >> 2, kq = t & 3;
    const float4 v = *(const float4*)(in + ((size_t)b * I_ + i) * K_ + kq * 4);
    lds[b][kq * 4 + 0] = v.x; lds[b][kq * 4 + 1] = v.y;
    lds[b][kq * 4 + 2] = v.z; lds[b][kq * 4 + 3] = v.w;
    __syncthreads();
#pragma unroll
    for (int q = 0; q < 4; ++q) {
        const int j = t + q * 256;          // j = k*64 + b
        const int k = j >> 6, bb = j & 63;
        inT[(size_t)i * (K_ * B_) + j] = lds[bb][k];
    }
}

// ---------------- pack inputs into MFMA A-fragment order (bf16) ----------------
__global__ __launch_bounds__(256) void k_xfrag(const float* __restrict__ in,
                                               uint4* __restrict__ xfrag) {
    const int tid = blockIdx.x * 256 + threadIdx.x;    // [m][kk][l]
    const int l = tid & 63, kk = (tid >> 6) & 1023, m = tid >> 16;
    const int b = m * 16 + (l & 15), g = l >> 4;
    const int i = 2 * kk + (g >> 1), k0 = 8 * (g & 1);
    const float* src = in + ((size_t)b * I_ + i) * K_ + k0;
    const float4 f0 = *(const float4*)src;
    const float4 f1 = *(const float4*)(src + 4);
    uint4 o;
    o.x = pk_bf16(f0.x, f0.y); o.y = pk_bf16(f0.z, f0.w);
    o.z = pk_bf16(f1.x, f1.y); o.w = pk_bf16(f1.z, f1.w);
    xfrag[tid] = o;
}

// ---------------- MFMA s-sweep (round 8, verified) ----------------
template<int UNIFORM>
__global__ __launch_bounds__(512, 2) void k_sweep_mfma(const float* __restrict__ W,
                                                       const uint4* __restrict__ xfrag,
                                                       const float* __restrict__ cT,
                                                       float* __restrict__ spart) {
    __shared__ float red[2][B_][D_ + 1];
    const int n = blockIdx.y, ch = blockIdx.x;
    const int t = threadIdx.x, w = t >> 6, l = t & 63;
    const int m = w >> 1, ks = w & 1;
    const int g = l >> 4;

    f32x4_t acc0 = {0.f, 0.f, 0.f, 0.f};
    f32x4_t acc1 = {0.f, 0.f, 0.f, 0.f};

    const uint4* xf = xfrag + (size_t)m * 65536 + l;           // + kk*64
    const float* wb = W + (size_t)n * (I_ * 512);
    const int wlane = (g >> 1) * 512 + (l & 15) * 16 + (g & 1) * 8;
    const int kk0 = ch * 64 + ks * 32;

    for (int tt = 0; tt < 32; ++tt) {
        const int kk = kk0 + tt;
        union { uint4 q; unsigned int u[4]; } xv;
        xv.q = xf[(size_t)kk * 64];
        union { unsigned int u[4]; short8_t v; } af;
        if (UNIFORM) {
            af.u[0] = xv.u[0]; af.u[1] = xv.u[1];
            af.u[2] = xv.u[2]; af.u[3] = xv.u[3];
        } else {
            const float c = cT[((size_t)n * I_ + 2 * kk + (l >> 5)) * B_
                               + m * 16 + (l & 15)];
#pragma unroll
            for (int p = 0; p < 4; ++p) {
                const unsigned int uu = xv.u[p];
                const float lo = __uint_as_float(uu << 16);
                const float hi = __uint_as_float(uu & 0xffff0000u);
                af.u[p] = pk_bf16(lo * c, hi * c);
            }
        }
        const float* wp = wb + (size_t)kk * 1024 + wlane;
        const short8_t bf0 = pack8(*(const float4*)wp, *(const float4*)(wp + 4));
        const short8_t bf1 = pack8(*(const float4*)(wp + 256), *(const float4*)(wp + 260));

        acc0 = __builtin_amdgcn_mfma_f32_16x16x32_bf16(af.v, bf0, acc0, 0, 0, 0);
        acc1 = __builtin_amdgcn_mfma_f32_16x16x32_bf16(af.v, bf1, acc1, 0, 0, 0);
    }

#pragma unroll
    for (int r = 0; r < 4; ++r) {
        const int row = m * 16 + (l >> 4) * 4 + r;
        red[ks][row][(l & 15)]      = acc0[r];
        red[ks][row][16 + (l & 15)] = acc1[r];
    }
    __syncthreads();
#pragma unroll
    for (int q = 0; q < 4; ++q) {
        const int j = q * 512 + t;                  // j = b*32 + d
        const int b = j >> 5, d = j & 31;
        spart[((size_t)n * SCH_ + ch) * (B_ * D_) + j] = red[0][b][d] + red[1][b][d];
    }
}

// ---------------- reduce partials + squash ----------------
template<int FINAL>
__global__ __launch_bounds__(256) void k_reduce(const float* __restrict__ spart,
                                                float* __restrict__ outT,
                                                float* __restrict__ out,
                                                float prescale) {
    const int gt = blockIdx.x * 256 + threadIdx.x;   // N*B*D threads
    const int n = gt >> 11;
    const int rem = gt & 2047;                        // b*32 + d
    const int b = rem >> 5, d = rem & 31;
    const float* sp = spart + (size_t)n * (SCH_ * B_ * D_) + rem;
    float s = 0.f;
#pragma unroll
    for (int p = 0; p < SCH_; ++p) s += sp[p * (B_ * D_)];
    s *= prescale;

    float sq = s * s;
#pragma unroll
    for (int off = 16; off >= 1; off >>= 1) sq += __shfl_xor(sq, off, 64);
    const float scale = sq / ((1.0f + sq) * sqrtf(sq + 1e-7f));
    const float o = scale * s;
    if (FINAL) {
        out[((size_t)b * N_ + n) * D_ + d] = o;       // [B][N][D]
    } else {
        outT[((size_t)n * D_ + d) * B_ + b] = o;      // [N][D][B]
    }
}

// ---------------- MFMA b-update ----------------
// Per (n,i): z[k][b] = sum_d W[n,i,d,k]*o[d][b] (one 16x16x32 MFMA, M=k, K=d,
// N=b-tile of 16), then g[b] = sum_k x[b,i,k]*z[k][b] via epilogue + shfl.
// Block 512 thr = 8 waves: wave = (ig = w>>2 in {0,1}) x (btile = w&3).
template<int FIRST>
__global__ __launch_bounds__(512, 2) void k_update_mfma(const float* __restrict__ W,
                                                        const float* __restrict__ inT,
                                                        const float* __restrict__ outT,
                                                        float* __restrict__ bT) {
    const int n = blockIdx.y, ch = blockIdx.x;
    const int t = threadIdx.x, w = t >> 6, l = t & 63;
    const int btile = w & 3;          // 16 b's
    const int ig = w >> 2;            // i-group of 32
    const int g = l >> 4;
    const int kl = l & 15;            // A-row (k) / B,C-col (b')

    // B fragment: o[d= 8g+j][b' = btile*16+kl], packed bf16
    union { unsigned int u[4]; short8_t v; } of;
    {
        const float* op = outT + (size_t)n * (D_ * B_) + btile * 16 + kl;
#pragma unroll
        for (int p = 0; p < 4; ++p) {
            const float e0 = op[(8 * g + 2 * p) * B_];
            const float e1 = op[(8 * g + 2 * p + 1) * B_];
            of.u[p] = pk_bf16(e0, e1);
        }
    }

    const float* wbase = W + ((size_t)n * I_ + ch * 64 + ig * 32) * 512;

    for (int tt = 0; tt < 32; ++tt) {
        const int i = ch * 64 + ig * 32 + tt;
        const float* wp = wbase + (size_t)tt * 512;
        // A fragment: A[row=kl][kappa=d=8g+j] = W[..][d][kl]  (addr d*16+kl)
        union { unsigned int u[4]; short8_t v; } af;
#pragma unroll
        for (int p = 0; p < 4; ++p) {
            const float e0 = wp[(8 * g + 2 * p) * 16 + kl];
            const float e1 = wp[(8 * g + 2 * p + 1) * 16 + kl];
            af.u[p] = pk_bf16(e0, e1);
        }
        f32x4_t acc = {0.f, 0.f, 0.f, 0.f};
        acc = __builtin_amdgcn_mfma_f32_16x16x32_bf16(af.v, of.v, acc, 0, 0, 0);
        // C: col=kl=b', row=4g+r=k. g[b'] = sum_k x[b',i,k]*z[k][b']
        float gp = 0.f;
        const float* xp = inT + (size_t)i * (K_ * B_) + btile * 16 + kl;
#pragma unroll
        for (int r = 0; r < 4; ++r)
            gp = fmaf(acc[r], xp[(4 * g + r) * B_], gp);
        gp += __shfl_xor(gp, 16, 64);
        gp += __shfl_xor(gp, 32, 64);
        if (l < 16) {
            const size_t bi = ((size_t)n * I_ + i) * B_ + btile * 16 + l;
            bT[bi] = FIRST ? gp : (bT[bi] + gp);
        }
    }
}

// ---------------- softmax over n: cT[n][i][b] = softmax_n(bT) ----------------
__global__ __launch_bounds__(256) void k_softmax(const float* __restrict__ bT,
                                                 float* __restrict__ cT) {
    const int t = threadIdx.x, w = t >> 6, lane = t & 63;
    const int i = blockIdx.x * 4 + w;
    float v[N_];
#pragma unroll
    for (int n = 0; n < N_; ++n) v[n] = bT[((size_t)n * I_ + i) * B_ + lane];
    float m = v[0];
#pragma unroll
    for (int n = 1; n < N_; ++n) m = fmaxf(m, v[n]);
    float sum = 0.f;
#pragma unroll
    for (int n = 0; n < N_; ++n) { v[n] = __expf(v[n] - m); sum += v[n]; }
    const float inv = 1.0f / sum;
#pragma unroll
    for (int n = 0; n < N_; ++n)
        cT[((size_t)n * I_ + i) * B_ + lane] = v[n] * inv;
}

extern "C" void kernel_launch(void* const* d_in, const int* in_sizes, int n_in,
                              void* d_out, int out_size, void* d_ws, size_t ws_size,
                              hipStream_t stream) {
    const float* inputs = (const float*)d_in[0];
    const float* W      = (const float*)d_in[1];
    float* out = (float*)d_out;
    float* ws  = (float*)d_ws;
    float* inT   = ws + OFF_INT;
    float* cT    = ws + OFF_CT;
    float* bT    = ws + OFF_BT;
    float* spart = ws + OFF_SPART;
    float* outT  = ws + OFF_OUTT;
    uint4* xfrag = (uint4*)(ws + OFF_XFRAG);

    k_transpose<<<I_, 256, 0, stream>>>(inputs, inT);
    k_xfrag<<<1024, 256, 0, stream>>>(inputs, xfrag);
    // r = 0 (uniform c = 1/N, applied as prescale in k_reduce)
    k_sweep_mfma<1><<<dim3(SCH_, N_), 512, 0, stream>>>(W, xfrag, cT, spart);
    k_reduce<0><<<256, 256, 0, stream>>>(spart, outT, out, 1.0f / N_);
    k_update_mfma<1><<<dim3(CH_, N_), 512, 0, stream>>>(W, inT, outT, bT);
    k_softmax<<<I_ / 4, 256, 0, stream>>>(bT, cT);
    // r = 1
    k_sweep_mfma<0><<<dim3(SCH_, N_), 512, 0, stream>>>(W, xfrag, cT, spart);
    k_reduce<0><<<256, 256, 0, stream>>>(spart, outT, out, 1.0f);
    k_update_mfma<0><<<dim3(CH_, N_), 512, 0, stream>>>(W, inT, outT, bT);
    k_softmax<<<I_ / 4, 256, 0, stream>>>(bT, cT);
    // r = 2
    k_sweep_mfma<0><<<dim3(SCH_, N_), 512, 0, stream>>>(W, xfrag, cT, spart);
    k_reduce<1><<<256, 256, 0, stream>>>(spart, outT, out, 1.0f);
}

// Round 11
// 204.624 us; speedup vs baseline: 12.2439x; 1.1011x over previous
//
#include <hip/hip_runtime.h>
#include <hip/hip_bf16.h>
#include <math.h>

#define B_ 64
#define I_ 2048
#define K_ 16
#define N_ 32
#define D_ 32
#define CH_ 32      // i-chunks (64 i each) for update
#define SCH_ 16     // i-chunks for mfma sweep (128 i each)

typedef __attribute__((ext_vector_type(8))) short short8_t;   // 8 bf16
typedef __attribute__((ext_vector_type(4))) float f32x4_t;

// ws offsets (floats)
#define OFF_INT   0u           // inT   [I][K][B]        2097152
#define OFF_CT    2097152u     // cT    [N][I][B]        4194304
#define OFF_BT    6291456u     // bT    [N][I][B]        4194304
#define OFF_SPART 10485760u    // spart [N][SCH][B][D]   1048576
#define OFF_OUTT  11534336u    // outT  [N][D][B]          65536
#define OFF_XFRAG 11599872u    // xfrag [4][1024][64] uint4 = 1048576 f-slots
#define OFF_WFS   12648448u    // wfs [N][1024][2][64] uint4 = 16777216 f-slots (64 MiB)
#define OFF_WFU   29425664u    // wfu [N][I][64] uint4       = 16777216 f-slots (64 MiB)
// total 46202880 floats = 176.25 MiB  (ws = 512 MiB per harness poison fills)

// ---------------- helpers ----------------
__device__ __forceinline__ unsigned int pk_bf16(float lo, float hi) {
    union { __hip_bfloat162 h2; unsigned int u; } cv;
    cv.h2 = __float22bfloat162_rn(float2{lo, hi});
    return cv.u;
}

// ---------------- transpose inputs[b][i][k] -> inT[i][k][b] ----------------
__global__ __launch_bounds__(256) void k_transpose(const float* __restrict__ in,
                                                   float* __restrict__ inT) {
    __shared__ float lds[B_][K_ + 1];
    const int i = blockIdx.x;
    const int t = threadIdx.x;
    const int b = t >> 2, kq = t & 3;
    const float4 v = *(const float4*)(in + ((size_t)b * I_ + i) * K_ + kq * 4);
    lds[b][kq * 4 + 0] = v.x; lds[b][kq * 4 + 1] = v.y;
    lds[b][kq * 4 + 2] = v.z; lds[b][kq * 4 + 3] = v.w;
    __syncthreads();
#pragma unroll
    for (int q = 0; q < 4; ++q) {
        const int j = t + q * 256;          // j = k*64 + b
        const int k = j >> 6, bb = j & 63;
        inT[(size_t)i * (K_ * B_) + j] = lds[bb][k];
    }
}

// ---------------- pack inputs into MFMA A-fragment order (bf16) ----------------
__global__ __launch_bounds__(256) void k_xfrag(const float* __restrict__ in,
                                               uint4* __restrict__ xfrag) {
    const int tid = blockIdx.x * 256 + threadIdx.x;    // [m][kk][l]
    const int l = tid & 63, kk = (tid >> 6) & 1023, m = tid >> 16;
    const int b = m * 16 + (l & 15), g = l >> 4;
    const int i = 2 * kk + (g >> 1), k0 = 8 * (g & 1);
    const float* src = in + ((size_t)b * I_ + i) * K_ + k0;
    const float4 f0 = *(const float4*)src;
    const float4 f1 = *(const float4*)(src + 4);
    uint4 o;
    o.x = pk_bf16(f0.x, f0.y); o.y = pk_bf16(f0.z, f0.w);
    o.z = pk_bf16(f1.x, f1.y); o.w = pk_bf16(f1.z, f1.w);
    xfrag[tid] = o;
}

// ---------------- pre-pack W -> bf16 fragments for BOTH consumers ----------------
// Block: 4 consecutive i of one n. Stages 2048 f to LDS, emits:
//  wfs[n][kk][nt][l]: sweep B-frag   (kk in [0,1024), n-stride 1024*2*64)
//  wfu[n][i][l]:      update A-frag  (pairs W[i][8g+2p(+1)][kl])
__global__ __launch_bounds__(256) void k_wpack(const float* __restrict__ W,
                                               uint4* __restrict__ wfs,
                                               uint4* __restrict__ wfu) {
    __shared__ __align__(16) float lds[2048];
    const int c = blockIdx.x;          // i-quad (0..511)
    const int n = blockIdx.y;
    const int t = threadIdx.x;
    const float4* s4 = (const float4*)(W + ((size_t)n * I_ + c * 4) * 512);
    float4* d4 = (float4*)lds;
    d4[t] = s4[t];
    d4[t + 256] = s4[t + 256];
    __syncthreads();
    // update A-frag: t -> (i_local, lane)
    {
        const int il = t >> 6, l = t & 63, g = l >> 4, kl = l & 15;
        const float* base = lds + il * 512;
        union { unsigned int u[4]; uint4 q; } o;
#pragma unroll
        for (int p = 0; p < 4; ++p)
            o.u[p] = pk_bf16(base[(8 * g + 2 * p) * 16 + kl],
                             base[(8 * g + 2 * p + 1) * 16 + kl]);
        wfu[((size_t)n * I_ + c * 4 + il) * 64 + l] = o.q;
    }
    // sweep B-frag: t -> (kk_local, nt, lane); global kk = c*2 + kkl in [0,1024)
    {
        const int kkl = t >> 7, r = t & 127, nt = r >> 6, l = r & 63, g = l >> 4;
        const float* p = lds + kkl * 1024 + (g >> 1) * 512 + nt * 256
                         + (l & 15) * 16 + (g & 1) * 8;
        const float4 f0 = *(const float4*)p;
        const float4 f1 = *(const float4*)(p + 4);
        union { unsigned int u[4]; uint4 q; } o;
        o.u[0] = pk_bf16(f0.x, f0.y); o.u[1] = pk_bf16(f0.z, f0.w);
        o.u[2] = pk_bf16(f1.x, f1.y); o.u[3] = pk_bf16(f1.z, f1.w);
        wfs[(((size_t)n * 1024 + c * 2 + kkl) * 2 + nt) * 64 + l] = o.q;
    }
}

// ---------------- MFMA s-sweep (packed B-frags) ----------------
template<int UNIFORM>
__global__ __launch_bounds__(512, 2) void k_sweep_mfma(const uint4* __restrict__ wfs,
                                                       const uint4* __restrict__ xfrag,
                                                       const float* __restrict__ cT,
                                                       float* __restrict__ spart) {
    __shared__ float red[2][B_][D_ + 1];
    const int n = blockIdx.y, ch = blockIdx.x;
    const int t = threadIdx.x, w = t >> 6, l = t & 63;
    const int m = w >> 1, ks = w & 1;

    f32x4_t acc0 = {0.f, 0.f, 0.f, 0.f};
    f32x4_t acc1 = {0.f, 0.f, 0.f, 0.f};

    const uint4* xf = xfrag + (size_t)m * 65536 + l;            // + kk*64
    const uint4* wf = wfs + (size_t)n * (1024 * 128) + l;       // + kk*128 (+64 nt=1)
    const int kk0 = ch * 64 + ks * 32;

    for (int tt = 0; tt < 32; ++tt) {
        const int kk = kk0 + tt;
        union { uint4 q; unsigned int u[4]; } xv;
        xv.q = xf[(size_t)kk * 64];
        union { unsigned int u[4]; short8_t v; } af;
        if (UNIFORM) {
            af.u[0] = xv.u[0]; af.u[1] = xv.u[1];
            af.u[2] = xv.u[2]; af.u[3] = xv.u[3];
        } else {
            const float c = cT[((size_t)n * I_ + 2 * kk + (l >> 5)) * B_
                               + m * 16 + (l & 15)];
#pragma unroll
            for (int p = 0; p < 4; ++p) {
                const unsigned int uu = xv.u[p];
                const float lo = __uint_as_float(uu << 16);
                const float hi = __uint_as_float(uu & 0xffff0000u);
                af.u[p] = pk_bf16(lo * c, hi * c);
            }
        }
        union { uint4 q; short8_t v; } b0, b1;
        b0.q = wf[(size_t)kk * 128];
        b1.q = wf[(size_t)kk * 128 + 64];

        acc0 = __builtin_amdgcn_mfma_f32_16x16x32_bf16(af.v, b0.v, acc0, 0, 0, 0);
        acc1 = __builtin_amdgcn_mfma_f32_16x16x32_bf16(af.v, b1.v, acc1, 0, 0, 0);
    }

#pragma unroll
    for (int r = 0; r < 4; ++r) {
        const int row = m * 16 + (l >> 4) * 4 + r;
        red[ks][row][(l & 15)]      = acc0[r];
        red[ks][row][16 + (l & 15)] = acc1[r];
    }
    __syncthreads();
#pragma unroll
    for (int q = 0; q < 4; ++q) {
        const int j = q * 512 + t;                  // j = b*32 + d
        const int b = j >> 5, d = j & 31;
        spart[((size_t)n * SCH_ + ch) * (B_ * D_) + j] = red[0][b][d] + red[1][b][d];
    }
}

// ---------------- reduce partials + squash ----------------
template<int FINAL>
__global__ __launch_bounds__(256) void k_reduce(const float* __restrict__ spart,
                                                float* __restrict__ outT,
                                                float* __restrict__ out,
                                                float prescale) {
    const int gt = blockIdx.x * 256 + threadIdx.x;   // N*B*D threads
    const int n = gt >> 11;
    const int rem = gt & 2047;                        // b*32 + d
    const int b = rem >> 5, d = rem & 31;
    const float* sp = spart + (size_t)n * (SCH_ * B_ * D_) + rem;
    float s = 0.f;
#pragma unroll
    for (int p = 0; p < SCH_; ++p) s += sp[p * (B_ * D_)];
    s *= prescale;

    float sq = s * s;
#pragma unroll
    for (int off = 16; off >= 1; off >>= 1) sq += __shfl_xor(sq, off, 64);
    const float scale = sq / ((1.0f + sq) * sqrtf(sq + 1e-7f));
    const float o = scale * s;
    if (FINAL) {
        out[((size_t)b * N_ + n) * D_ + d] = o;       // [B][N][D]
    } else {
        outT[((size_t)n * D_ + d) * B_ + b] = o;      // [N][D][B]
    }
}

// ---------------- MFMA b-update (packed A-frags) ----------------
template<int FIRST>
__global__ __launch_bounds__(512, 2) void k_update_mfma(const uint4* __restrict__ wfu,
                                                        const float* __restrict__ inT,
                                                        const float* __restrict__ outT,
                                                        float* __restrict__ bT) {
    const int n = blockIdx.y, ch = blockIdx.x;
    const int t = threadIdx.x, w = t >> 6, l = t & 63;
    const int btile = w & 3;          // 16 b's
    const int ig = w >> 2;            // i-group of 32
    const int g = l >> 4;
    const int kl = l & 15;            // A-row (k) / B,C-col (b')

    // B fragment: o[d= 8g+j][b' = btile*16+kl], packed bf16
    union { unsigned int u[4]; short8_t v; } of;
    {
        const float* op = outT + (size_t)n * (D_ * B_) + btile * 16 + kl;
#pragma unroll
        for (int p = 0; p < 4; ++p) {
            const float e0 = op[(8 * g + 2 * p) * B_];
            const float e1 = op[(8 * g + 2 * p + 1) * B_];
            of.u[p] = pk_bf16(e0, e1);
        }
    }

    const uint4* wf = wfu + ((size_t)n * I_ + ch * 64 + ig * 32) * 64 + l;

    for (int tt = 0; tt < 32; ++tt) {
        const int i = ch * 64 + ig * 32 + tt;
        union { uint4 q; short8_t v; } af;
        af.q = wf[(size_t)tt * 64];
        f32x4_t acc = {0.f, 0.f, 0.f, 0.f};
        acc = __builtin_amdgcn_mfma_f32_16x16x32_bf16(af.v, of.v, acc, 0, 0, 0);
        // C: col=kl=b', row=4g+r=k. g[b'] = sum_k x[b',i,k]*z[k][b']
        float gp = 0.f;
        const float* xp = inT + (size_t)i * (K_ * B_) + btile * 16 + kl;
#pragma unroll
        for (int r = 0; r < 4; ++r)
            gp = fmaf(acc[r], xp[(4 * g + r) * B_], gp);
        gp += __shfl_xor(gp, 16, 64);
        gp += __shfl_xor(gp, 32, 64);
        if (l < 16) {
            const size_t bi = ((size_t)n * I_ + i) * B_ + btile * 16 + l;
            bT[bi] = FIRST ? gp : (bT[bi] + gp);
        }
    }
}

// ---------------- softmax over n: cT[n][i][b] = softmax_n(bT) ----------------
__global__ __launch_bounds__(256) void k_softmax(const float* __restrict__ bT,
                                                 float* __restrict__ cT) {
    const int t = threadIdx.x, w = t >> 6, lane = t & 63;
    const int i = blockIdx.x * 4 + w;
    float v[N_];
#pragma unroll
    for (int n = 0; n < N_; ++n) v[n] = bT[((size_t)n * I_ + i) * B_ + lane];
    float m = v[0];
#pragma unroll
    for (int n = 1; n < N_; ++n) m = fmaxf(m, v[n]);
    float sum = 0.f;
#pragma unroll
    for (int n = 0; n < N_; ++n) { v[n] = __expf(v[n] - m); sum += v[n]; }
    const float inv = 1.0f / sum;
#pragma unroll
    for (int n = 0; n < N_; ++n)
        cT[((size_t)n * I_ + i) * B_ + lane] = v[n] * inv;
}

extern "C" void kernel_launch(void* const* d_in, const int* in_sizes, int n_in,
                              void* d_out, int out_size, void* d_ws, size_t ws_size,
                              hipStream_t stream) {
    const float* inputs = (const float*)d_in[0];
    const float* W      = (const float*)d_in[1];
    float* out = (float*)d_out;
    float* ws  = (float*)d_ws;
    float* inT   = ws + OFF_INT;
    float* cT    = ws + OFF_CT;
    float* bT    = ws + OFF_BT;
    float* spart = ws + OFF_SPART;
    float* outT  = ws + OFF_OUTT;
    uint4* xfrag = (uint4*)(ws + OFF_XFRAG);
    uint4* wfs   = (uint4*)(ws + OFF_WFS);
    uint4* wfu   = (uint4*)(ws + OFF_WFU);

    k_transpose<<<I_, 256, 0, stream>>>(inputs, inT);
    k_xfrag<<<1024, 256, 0, stream>>>(inputs, xfrag);
    k_wpack<<<dim3(512, N_), 256, 0, stream>>>(W, wfs, wfu);
    // r = 0 (uniform c = 1/N, applied as prescale in k_reduce)
    k_sweep_mfma<1><<<dim3(SCH_, N_), 512, 0, stream>>>(wfs, xfrag, cT, spart);
    k_reduce<0><<<256, 256, 0, stream>>>(spart, outT, out, 1.0f / N_);
    k_update_mfma<1><<<dim3(CH_, N_), 512, 0, stream>>>(wfu, inT, outT, bT);
    k_softmax<<<I_ / 4, 256, 0, stream>>>(bT, cT);
    // r = 1
    k_sweep_mfma<0><<<dim3(SCH_, N_), 512, 0, stream>>>(wfs, xfrag, cT, spart);
    k_reduce<0><<<256, 256, 0, stream>>>(spart, outT, out, 1.0f);
    k_update_mfma<0><<<dim3(CH_, N_), 512, 0, stream>>>(wfu, inT, outT, bT);
    k_softmax<<<I_ / 4, 256, 0, stream>>>(bT, cT);
    // r = 2
    k_sweep_mfma<0><<<dim3(SCH_, N_), 512, 0, stream>>>(wfs, xfrag, cT, spart);
    k_reduce<1><<<256, 256, 0, stream>>>(spart, outT, out, 1.0f);
}

// Round 12
// 175.591 us; speedup vs baseline: 14.2683x; 1.1653x over previous
//
#include <hip/hip_runtime.h>
#include <hip/hip_bf16.h>
#include <math.h>

#define B_ 64
#define I_ 2048
#define K_ 16
#define N_ 32
#define D_ 32
#define SCH_ 16     // i-chunks for mfma sweep (128 i each)

typedef __attribute__((ext_vector_type(8))) short short8_t;   // 8 bf16
typedef __attribute__((ext_vector_type(4))) float f32x4_t;

// ws offsets (floats)
#define OFF_INT   0u           // inT   [I][K][B]        2097152
#define OFF_CT    2097152u     // cT    [N][I][B]        4194304
#define OFF_BT    6291456u     // bT    [N][I][B]        4194304
#define OFF_SPART 10485760u    // spart [N][SCH][B][D]   1048576
#define OFF_OFRAG 11534336u    // ofrag [N][4][64] uint4 =  32768 f-slots
#define OFF_XFRAG 11599872u    // xfrag [4][1024][64] uint4 = 1048576 f-slots
#define OFF_WFS   12648448u    // wfs [N][1024][2][64] uint4 = 16777216 (64 MiB)
#define OFF_WFU   29425664u    // wfu [N][I][64] uint4       = 16777216 (64 MiB)
// total 176.25 MiB (ws = 512 MiB per harness poison fills)

__device__ __forceinline__ unsigned int pk_bf16(float lo, float hi) {
    union { __hip_bfloat162 h2; unsigned int u; } cv;
    cv.h2 = __float22bfloat162_rn(float2{lo, hi});
    return cv.u;
}

// ---------------- fused: transpose inputs -> inT  +  pack xfrag ----------------
__global__ __launch_bounds__(256) void k_prep(const float* __restrict__ in,
                                              float* __restrict__ inT,
                                              uint4* __restrict__ xfrag) {
    __shared__ float lds[B_][K_ + 1];
    const int i = blockIdx.x;
    const int t = threadIdx.x;
    const int b = t >> 2, kq = t & 3;
    const float4 v = *(const float4*)(in + ((size_t)b * I_ + i) * K_ + kq * 4);
    lds[b][kq * 4 + 0] = v.x; lds[b][kq * 4 + 1] = v.y;
    lds[b][kq * 4 + 2] = v.z; lds[b][kq * 4 + 3] = v.w;
    __syncthreads();
#pragma unroll
    for (int q = 0; q < 4; ++q) {
        const int j = t + q * 256;          // j = k*64 + b
        const int k = j >> 6, bb = j & 63;
        inT[(size_t)i * (K_ * B_) + j] = lds[bb][k];
    }
    // xfrag entries for this i: 128 threads, one uint4 each
    if (t < 128) {
        const int m = t >> 5, r = t & 31, gl = r >> 4, kl = r & 15;
        const int bb = m * 16 + kl, k0 = 8 * gl;
        union { unsigned int u[4]; uint4 q; } o;
#pragma unroll
        for (int p = 0; p < 4; ++p)
            o.u[p] = pk_bf16(lds[bb][k0 + 2 * p], lds[bb][k0 + 2 * p + 1]);
        xfrag[((size_t)m * 1024 + (i >> 1)) * 64 + (2 * (i & 1) + gl) * 16 + kl] = o.q;
    }
}

// ---------------- pre-pack W -> bf16 fragments (verified r11) ----------------
__global__ __launch_bounds__(256) void k_wpack(const float* __restrict__ W,
                                               uint4* __restrict__ wfs,
                                               uint4* __restrict__ wfu) {
    __shared__ __align__(16) float lds[2048];
    const int c = blockIdx.x;          // i-quad (0..511)
    const int n = blockIdx.y;
    const int t = threadIdx.x;
    const float4* s4 = (const float4*)(W + ((size_t)n * I_ + c * 4) * 512);
    float4* d4 = (float4*)lds;
    d4[t] = s4[t];
    d4[t + 256] = s4[t + 256];
    __syncthreads();
    {
        const int il = t >> 6, l = t & 63, g = l >> 4, kl = l & 15;
        const float* base = lds + il * 512;
        union { unsigned int u[4]; uint4 q; } o;
#pragma unroll
        for (int p = 0; p < 4; ++p)
            o.u[p] = pk_bf16(base[(8 * g + 2 * p) * 16 + kl],
                             base[(8 * g + 2 * p + 1) * 16 + kl]);
        wfu[((size_t)n * I_ + c * 4 + il) * 64 + l] = o.q;
    }
    {
        const int kkl = t >> 7, r = t & 127, nt = r >> 6, l = r & 63, g = l >> 4;
        const float* p = lds + kkl * 1024 + (g >> 1) * 512 + nt * 256
                         + (l & 15) * 16 + (g & 1) * 8;
        const float4 f0 = *(const float4*)p;
        const float4 f1 = *(const float4*)(p + 4);
        union { unsigned int u[4]; uint4 q; } o;
        o.u[0] = pk_bf16(f0.x, f0.y); o.u[1] = pk_bf16(f0.z, f0.w);
        o.u[2] = pk_bf16(f1.x, f1.y); o.u[3] = pk_bf16(f1.z, f1.w);
        wfs[(((size_t)n * 1024 + c * 2 + kkl) * 2 + nt) * 64 + l] = o.q;
    }
}

// ---------------- MFMA s-sweep (verified r11) ----------------
template<int UNIFORM>
__global__ __launch_bounds__(512, 2) void k_sweep_mfma(const uint4* __restrict__ wfs,
                                                       const uint4* __restrict__ xfrag,
                                                       const float* __restrict__ cT,
                                                       float* __restrict__ spart) {
    __shared__ float red[2][B_][D_ + 1];
    const int n = blockIdx.y, ch = blockIdx.x;
    const int t = threadIdx.x, w = t >> 6, l = t & 63;
    const int m = w >> 1, ks = w & 1;

    f32x4_t acc0 = {0.f, 0.f, 0.f, 0.f};
    f32x4_t acc1 = {0.f, 0.f, 0.f, 0.f};

    const uint4* xf = xfrag + (size_t)m * 65536 + l;            // + kk*64
    const uint4* wf = wfs + (size_t)n * (1024 * 128) + l;       // + kk*128 (+64 nt=1)
    const int kk0 = ch * 64 + ks * 32;

    for (int tt = 0; tt < 32; ++tt) {
        const int kk = kk0 + tt;
        union { uint4 q; unsigned int u[4]; } xv;
        xv.q = xf[(size_t)kk * 64];
        union { unsigned int u[4]; short8_t v; } af;
        if (UNIFORM) {
            af.u[0] = xv.u[0]; af.u[1] = xv.u[1];
            af.u[2] = xv.u[2]; af.u[3] = xv.u[3];
        } else {
            const float c = cT[((size_t)n * I_ + 2 * kk + (l >> 5)) * B_
                               + m * 16 + (l & 15)];
#pragma unroll
            for (int p = 0; p < 4; ++p) {
                const unsigned int uu = xv.u[p];
                const float lo = __uint_as_float(uu << 16);
                const float hi = __uint_as_float(uu & 0xffff0000u);
                af.u[p] = pk_bf16(lo * c, hi * c);
            }
        }
        union { uint4 q; short8_t v; } b0, b1;
        b0.q = wf[(size_t)kk * 128];
        b1.q = wf[(size_t)kk * 128 + 64];

        acc0 = __builtin_amdgcn_mfma_f32_16x16x32_bf16(af.v, b0.v, acc0, 0, 0, 0);
        acc1 = __builtin_amdgcn_mfma_f32_16x16x32_bf16(af.v, b1.v, acc1, 0, 0, 0);
    }

#pragma unroll
    for (int r = 0; r < 4; ++r) {
        const int row = m * 16 + (l >> 4) * 4 + r;
        red[ks][row][(l & 15)]      = acc0[r];
        red[ks][row][16 + (l & 15)] = acc1[r];
    }
    __syncthreads();
#pragma unroll
    for (int q = 0; q < 4; ++q) {
        const int j = q * 512 + t;                  // j = b*32 + d
        const int b = j >> 5, d = j & 31;
        spart[((size_t)n * SCH_ + ch) * (B_ * D_) + j] = red[0][b][d] + red[1][b][d];
    }
}

// ---------------- reduce + squash; emit ofrag (update B-frags) or out ----------
template<int FINAL>
__global__ __launch_bounds__(256) void k_reduce(const float* __restrict__ spart,
                                                unsigned int* __restrict__ ofrag_u32,
                                                float* __restrict__ out,
                                                float prescale) {
    const int gt = blockIdx.x * 256 + threadIdx.x;   // N*B*D threads
    const int n = gt >> 11;
    const int rem = gt & 2047;                        // b*32 + d
    const int b = rem >> 5, d = rem & 31;
    const float* sp = spart + (size_t)n * (SCH_ * B_ * D_) + rem;
    float s = 0.f;
#pragma unroll
    for (int p = 0; p < SCH_; ++p) s += sp[p * (B_ * D_)];
    s *= prescale;

    float sq = s * s;
#pragma unroll
    for (int off = 16; off >= 1; off >>= 1) sq += __shfl_xor(sq, off, 64);
    const float scale = sq / ((1.0f + sq) * sqrtf(sq + 1e-7f));
    const float o = scale * s;
    if (FINAL) {
        out[((size_t)b * N_ + n) * D_ + d] = o;       // [B][N][D]
    } else {
        // pack pairs (d even, d+1) into ofrag[n][b>>4][(d>>3)*16 + (b&15)].u[(d&7)>>1]
        const float o_next = __shfl_down(o, 1, 64);
        if ((d & 1) == 0) {
            const unsigned int val = pk_bf16(o, o_next);
            const int l = (d >> 3) * 16 + (b & 15);
            ofrag_u32[(((n * 4 + (b >> 4)) * 64) + l) * 4 + ((d & 7) >> 1)] = val;
        }
    }
}

// ---------------- fused b-update + softmax ----------------
// Block = 2 i (512 thr, 8 waves = 4 btile x 2 i). Loop n in-register (bn[32]),
// FIRST: bT = g; else bn += bT. Then softmax over n -> cT.
template<int FIRST>
__global__ __launch_bounds__(512, 2) void k_updsm(const uint4* __restrict__ wfu,
                                                  const float* __restrict__ inT,
                                                  const uint4* __restrict__ ofrag,
                                                  float* __restrict__ bT,
                                                  float* __restrict__ cT) {
    const int t = threadIdx.x, w = t >> 6, l = t & 63;
    const int btile = w & 3;
    const int i = blockIdx.x * 2 + (w >> 2);
    const int g = l >> 4, kl = l & 15;
    const int bp = btile * 16 + kl;           // b'

    // x[k = 4g+r][b'] hoisted (n-independent)
    float x4[4];
    {
        const float* xp = inT + (size_t)i * (K_ * B_) + bp;
#pragma unroll
        for (int r = 0; r < 4; ++r) x4[r] = xp[(4 * g + r) * B_];
    }

    float bn[N_];
#pragma unroll
    for (int n = 0; n < N_; ++n) {
        union { uint4 q; short8_t v; } of, af;
        of.q = ofrag[(n * 4 + btile) * 64 + l];
        af.q = wfu[((size_t)n * I_ + i) * 64 + l];
        f32x4_t acc = {0.f, 0.f, 0.f, 0.f};
        acc = __builtin_amdgcn_mfma_f32_16x16x32_bf16(af.v, of.v, acc, 0, 0, 0);
        float gp = 0.f;
#pragma unroll
        for (int r = 0; r < 4; ++r) gp = fmaf(acc[r], x4[r], gp);
        gp += __shfl_xor(gp, 16, 64);
        gp += __shfl_xor(gp, 32, 64);       // all lanes now hold full sum for b'
        const size_t bi = ((size_t)n * I_ + i) * B_ + bp;
        if (FIRST) {
            if (l < 16) bT[bi] = gp;
        } else {
            gp += bT[bi];
        }
        bn[n] = gp;
    }

    // softmax over n (registers)
    float mx = bn[0];
#pragma unroll
    for (int n = 1; n < N_; ++n) mx = fmaxf(mx, bn[n]);
    float sum = 0.f;
#pragma unroll
    for (int n = 0; n < N_; ++n) { bn[n] = __expf(bn[n] - mx); sum += bn[n]; }
    const float inv = 1.0f / sum;
    if (l < 16) {
#pragma unroll
        for (int n = 0; n < N_; ++n)
            cT[((size_t)n * I_ + i) * B_ + bp] = bn[n] * inv;
    }
}

extern "C" void kernel_launch(void* const* d_in, const int* in_sizes, int n_in,
                              void* d_out, int out_size, void* d_ws, size_t ws_size,
                              hipStream_t stream) {
    const float* inputs = (const float*)d_in[0];
    const float* W      = (const float*)d_in[1];
    float* out = (float*)d_out;
    float* ws  = (float*)d_ws;
    float* inT   = ws + OFF_INT;
    float* cT    = ws + OFF_CT;
    float* bT    = ws + OFF_BT;
    float* spart = ws + OFF_SPART;
    unsigned int* ofrag_u32 = (unsigned int*)(ws + OFF_OFRAG);
    uint4* ofrag = (uint4*)(ws + OFF_OFRAG);
    uint4* xfrag = (uint4*)(ws + OFF_XFRAG);
    uint4* wfs   = (uint4*)(ws + OFF_WFS);
    uint4* wfu   = (uint4*)(ws + OFF_WFU);

    k_prep<<<I_, 256, 0, stream>>>(inputs, inT, xfrag);
    k_wpack<<<dim3(512, N_), 256, 0, stream>>>(W, wfs, wfu);
    // r = 0 (uniform c = 1/N as prescale)
    k_sweep_mfma<1><<<dim3(SCH_, N_), 512, 0, stream>>>(wfs, xfrag, cT, spart);
    k_reduce<0><<<256, 256, 0, stream>>>(spart, ofrag_u32, out, 1.0f / N_);
    k_updsm<1><<<I_ / 2, 512, 0, stream>>>(wfu, inT, ofrag, bT, cT);
    // r = 1
    k_sweep_mfma<0><<<dim3(SCH_, N_), 512, 0, stream>>>(wfs, xfrag, cT, spart);
    k_reduce<0><<<256, 256, 0, stream>>>(spart, ofrag_u32, out, 1.0f);
    k_updsm<0><<<I_ / 2, 512, 0, stream>>>(wfu, inT, ofrag, bT, cT);
    // r = 2
    k_sweep_mfma<0><<<dim3(SCH_, N_), 512, 0, stream>>>(wfs, xfrag, cT, spart);
    k_reduce<1><<<256, 256, 0, stream>>>(spart, ofrag_u32, out, 1.0f);
}